// Round 7
// baseline (486.625 us; speedup 1.0000x reference)
//
#include <hip/hip_runtime.h>
#include <hip/hip_bf16.h>

#define NTOK 4096
#define EMB 1024
#define DMODEL 512
#define NHEAD 8
#define NLAYER 2
#define NCLS 2
#define KMAX 160

typedef __attribute__((ext_vector_type(8))) short bf16x8;
typedef __attribute__((ext_vector_type(4))) float f32x4;

__device__ inline unsigned short f2b(float f) {
    unsigned u = __float_as_uint(f);
    u = u + 0x7FFFu + ((u >> 16) & 1u);
    return (unsigned short)(u >> 16);
}
__device__ inline float b2f(unsigned short s) {
    return __uint_as_float((unsigned)s << 16);
}

// v_dot2_f32_bf16: d = a.lo*b.lo + a.hi*b.hi + c  (packed bf16 pairs)
__device__ inline float dot2bf(unsigned a, unsigned b, float c) {
    float d;
    asm("v_dot2_f32_bf16 %0, %1, %2, %3" : "=v"(d) : "v"(a), "v"(b), "v"(c));
    return d;
}

__device__ inline float wsum(float v) {
    for (int o = 32; o > 0; o >>= 1) v += __shfl_xor(v, o, 64);
    return v;
}
__device__ inline float wmax(float v) {
    for (int o = 32; o > 0; o >>= 1) v = fmaxf(v, __shfl_xor(v, o, 64));
    return v;
}

// async global->LDS, 16 B per lane. dest must be wave-uniform base + lane*16.
typedef __attribute__((address_space(3))) unsigned lds_u32_t;
typedef __attribute__((address_space(1))) const unsigned glb_u32_t;
__device__ inline void gload16(const void* g, void* l) {
    __builtin_amdgcn_global_load_lds((glb_u32_t*)(unsigned long long)g,
                                     (lds_u32_t*)(unsigned)(unsigned long long)l,
                                     16, 0, 0);
}

// Balanced head->XCD schedule: work blocks of 4 rows, 1024 blocks/head.
__device__ const int g_s0cnt[8]  = {576, 448, 720, 144, 365, 490, 460, 159};
__device__ const int g_s0h[8]    = {7, 7, 6, 6, 5, 4, 3, 2};
__device__ const int g_s0base[8] = {0, 576, 160, 880, 659, 534, 564, 865};
__device__ const int g_s1cnt[8]  = {0, 160, 0, 659, 534, 564, 865, 1024};
__device__ const int g_s1h[8]    = {0, 6, 0, 5, 4, 3, 2, 1};
#define ATTN_BLOCKS (2207 * 8)

// ---------------- weight convert+transpose: W[K][N] f32 -> Wt[N][K] bf16 (z = layer) ---
__global__ __launch_bounds__(256) void wcvt_k(const float* __restrict__ W,
                                              unsigned short* __restrict__ Wt,
                                              int K, int N)
{
    __shared__ unsigned short tile[64][72];
    size_t ls = (size_t)K * N * blockIdx.z;
    const float* Wl = W + ls;
    unsigned short* Wtl = Wt + ls;
    int k0 = blockIdx.x * 64, n0 = blockIdx.y * 64;
    int t = threadIdx.x;
    int kl = t >> 2, nb = (t & 3) * 16;
    const float* src = Wl + (size_t)(k0 + kl) * N + n0 + nb;
#pragma unroll
    for (int i = 0; i < 4; i++) {
        float4 v = *(const float4*)(src + 4 * i);
        tile[nb + 4 * i + 0][kl] = f2b(v.x);
        tile[nb + 4 * i + 1][kl] = f2b(v.y);
        tile[nb + 4 * i + 2][kl] = f2b(v.z);
        tile[nb + 4 * i + 3][kl] = f2b(v.w);
    }
    __syncthreads();
    int nl = t >> 2, ks = (t & 3) * 16;
    unsigned short* dst = Wtl + (size_t)(n0 + nl) * K + k0 + ks;
    *(uint4*)dst = *(const uint4*)&tile[nl][ks];
    *(uint4*)(dst + 8) = *(const uint4*)&tile[nl][ks + 8];
}

// ---------------- x f32 -> bf16 flat ----------------
__global__ __launch_bounds__(256) void xcvt_k(const float* __restrict__ X,
                                              unsigned short* __restrict__ Xb)
{
    int i = (blockIdx.x * 256 + threadIdx.x) * 8;
    float4 a = *(const float4*)(X + i);
    float4 b = *(const float4*)(X + i + 4);
    unsigned short o[8];
    o[0] = f2b(a.x); o[1] = f2b(a.y); o[2] = f2b(a.z); o[3] = f2b(a.w);
    o[4] = f2b(b.x); o[5] = f2b(b.y); o[6] = f2b(b.z); o[7] = f2b(b.w);
    *(uint4*)(Xb + i) = *(const uint4*)o;
}

// ---------------- dsel[n][k] = distance[n][indices[n][k]] ----------------
__global__ __launch_bounds__(256) void dsel_k(const float* __restrict__ distance,
                                              const int* __restrict__ indices,
                                              float* __restrict__ dsel)
{
    int n = blockIdx.x, t = threadIdx.x;
    if (t < KMAX) {
        int idx = indices[(size_t)n * KMAX + t];
        dsel[(size_t)n * KMAX + t] = distance[(size_t)n * NTOK + idx];
    }
}

// ---------------- kn[n][h] = sum_d K[n,h,d]^2 from bf16 qkv ----------------
__global__ __launch_bounds__(512) void knb_k(const unsigned short* __restrict__ qkv,
                                             float* __restrict__ kn)
{
    int n = blockIdx.x;
    int hh = threadIdx.x >> 6, lane = threadIdx.x & 63;
    float kv = b2f(qkv[(size_t)n * 1536 + 512 + hh * 64 + lane]);
    float ks = wsum(kv * kv);
    if (lane == 0) kn[n * NHEAD + hh] = ks;
}

// ---------------- MFMA GEMM (m97 structure): C = epi(A_bf16[M,K] @ Wt[N,K]^T + bias) --
// Tile BM x BN, waves WM x WN, BK=32, global_load_lds staging, linear LDS.
// MODE 0: Cf=v  1: Cf=resid+relu(v)  2: Cb=bf16(gelu(v))  3: Cf=resid+v
// MODE 4: Cf=v, Cb=bf16(v)  5: Cb=bf16(v)
template <int BM, int BN, int WM, int WN, int MODE>
__global__ __launch_bounds__(256) void mgemm_k(
    const unsigned short* __restrict__ A, const unsigned short* __restrict__ Wt,
    const float* __restrict__ bias, const float* __restrict__ resid,
    float* __restrict__ Cf, unsigned short* __restrict__ Cb,
    int M, int N, int K)
{
    constexpr int SM = BM / WM;          // wave sub-tile rows
    constexpr int SN = BN / WN;          // wave sub-tile cols
    constexpr int MR = SM / 16;
    constexpr int NR = SN / 16;

    __shared__ unsigned short Asl[BM * 32];
    __shared__ unsigned short Bsl[BN * 32];

    int tid = threadIdx.x;
    int bm = blockIdx.x * BM, bn = blockIdx.y * BN;
    int lane = tid & 63, wid = tid >> 6;
    int wm = wid / WN, wn = wid % WN;
    int l15 = lane & 15, l4 = lane >> 4;

    f32x4 acc[MR][NR] = {};

    int sr = tid >> 2, sc = (tid & 3) * 8;              // staging row/col
    const unsigned short* Asrc = A  + (size_t)(bm + sr) * K + sc;
    const unsigned short* Bsrc = Wt + (size_t)(bn + sr) * K + sc;
    unsigned short* Adst = &Asl[sr * 32 + sc];
    unsigned short* Bdst = &Bsl[sr * 32 + sc];

    int arow0 = (wm * SM + l15) * 32 + l4 * 8;
    int brow0 = (wn * SN + l15) * 32 + l4 * 8;

    for (int k0 = 0; k0 < K; k0 += 32) {
#pragma unroll
        for (int i = 0; i < BM / 64; i++)
            gload16(Asrc + (size_t)(i * 64) * K + k0, Adst + i * 64 * 32);
#pragma unroll
        for (int i = 0; i < BN / 64; i++)
            gload16(Bsrc + (size_t)(i * 64) * K + k0, Bdst + i * 64 * 32);
        __syncthreads();     // drains vmcnt(0) before barrier

        bf16x8 af[MR], bfr[NR];
#pragma unroll
        for (int mr = 0; mr < MR; mr++) af[mr] = *(const bf16x8*)&Asl[arow0 + mr * 16 * 32];
#pragma unroll
        for (int nr = 0; nr < NR; nr++) bfr[nr] = *(const bf16x8*)&Bsl[brow0 + nr * 16 * 32];
#pragma unroll
        for (int mr = 0; mr < MR; mr++)
#pragma unroll
            for (int nr = 0; nr < NR; nr++)
                acc[mr][nr] = __builtin_amdgcn_mfma_f32_16x16x32_bf16(af[mr], bfr[nr], acc[mr][nr], 0, 0, 0);
        __syncthreads();
    }

#pragma unroll
    for (int mr = 0; mr < MR; mr++) {
#pragma unroll
        for (int nr = 0; nr < NR; nr++) {
            int col = bn + wn * SN + nr * 16 + l15;
            float bcol = bias[col];
#pragma unroll
            for (int r = 0; r < 4; r++) {
                int row = bm + wm * SM + mr * 16 + l4 * 4 + r;
                size_t off = (size_t)row * N + col;
                float v = acc[mr][nr][r] + bcol;
                if (MODE == 0) {
                    Cf[off] = v;
                } else if (MODE == 1) {
                    Cf[off] = resid[off] + fmaxf(v, 0.f);
                } else if (MODE == 2) {
                    float t3 = tanhf(0.7978845608028654f * (v + 0.044715f * v * v * v));
                    Cb[off] = f2b(0.5f * v * (1.f + t3));
                } else if (MODE == 3) {
                    Cf[off] = resid[off] + v;
                } else if (MODE == 4) {
                    Cf[off] = v;
                    Cb[off] = f2b(v);
                } else {
                    Cb[off] = f2b(v);
                }
            }
        }
    }
}

// ---------------- LayerNorm over D=512, one row per block ----------------
template <int OUTB>
__global__ __launch_bounds__(256) void ln_k(
    const float* __restrict__ X, const float* __restrict__ g,
    const float* __restrict__ bta, void* __restrict__ Yv, float eps)
{
    int row = blockIdx.x;
    int tid = threadIdx.x;
    const float* xr = X + (size_t)row * DMODEL;
    float v0 = xr[tid], v1 = xr[tid + 256];
    __shared__ float red[8];
    float s = wsum(v0 + v1);
    int wid = tid >> 6, lane = tid & 63;
    if (lane == 0) red[wid] = s;
    __syncthreads();
    float m = (red[0] + red[1] + red[2] + red[3]) * (1.f / DMODEL);
    float d0 = v0 - m, d1 = v1 - m;
    float sq = wsum(d0 * d0 + d1 * d1);
    if (lane == 0) red[4 + wid] = sq;
    __syncthreads();
    float var = (red[4] + red[5] + red[6] + red[7]) * (1.f / DMODEL);
    float rs = 1.0f / sqrtf(var + eps);
    float y0 = d0 * rs * g[tid] + bta[tid];
    float y1 = d1 * rs * g[tid + 256] + bta[tid + 256];
    if (OUTB) {
        unsigned short* Y = (unsigned short*)Yv;
        Y[(size_t)row * DMODEL + tid] = f2b(y0);
        Y[(size_t)row * DMODEL + tid + 256] = f2b(y1);
    } else {
        float* Y = (float*)Yv;
        Y[(size_t)row * DMODEL + tid] = y0;
        Y[(size_t)row * DMODEL + tid + 256] = y1;
    }
}

// ---------------- gathered attention, bf16 qkv, balanced head->XCD schedule --------
__global__ __launch_bounds__(256) void attn_k(
    const unsigned short* __restrict__ qkv,   // [n][1536] bf16
    const float* __restrict__ kn,             // [n][8]
    const int* __restrict__ indices, const float* __restrict__ dsel,
    const float* __restrict__ lam, unsigned short* __restrict__ xo, int layer)
{
    int xcd = blockIdx.x & 7;
    int t = blockIdx.x >> 3;
    int hh, blk;
    int c0 = g_s0cnt[xcd];
    if (t < c0) {
        hh = g_s0h[xcd]; blk = g_s0base[xcd] + t;
    } else {
        t -= c0;
        int c1 = g_s1cnt[xcd];
        if (t < c1) {
            hh = g_s1h[xcd]; blk = t;
        } else if (xcd == 7 && t - c1 < 1024) {
            hh = 0; blk = t - c1;
        } else {
            return;
        }
    }

    int wid = threadIdx.x >> 6, lane = threadIdx.x & 63;
    int n = blk * 4 + wid;
    int Kh = 32 + 16 * hh + (hh == 7 ? 16 : 0);   // 32..160

    __shared__ __align__(16) unsigned qsp[4][32];   // q as packed bf16 pairs
    __shared__ float asc[4][KMAX];
    __shared__ int   sidx[4][KMAX];

    const unsigned short* qrow = qkv + (size_t)n * 1536 + hh * 64;
    float qd = b2f(qrow[lane]);
    if (lane < 32) qsp[wid][lane] = ((const unsigned*)qrow)[lane];
    float qn2 = wsum(qd * qd);
    float sp = log1pf(expf(lam[layer * NHEAD + hh]));

    const int* irow = indices + (size_t)n * KMAX;
    const float* drow = dsel + (size_t)n * KMAX;

    // ---- Phase A: scores via v_dot2_f32_bf16, lane = neighbor ----
    float sc[3];
    int   sid[3];
#pragma unroll
    for (int j = 0; j < 3; j++) { sc[j] = -1e30f; sid[j] = 0; }

    const uint4* q4p = (const uint4*)&qsp[wid][0];
#pragma unroll
    for (int j = 0; j < 3; j++) {
        if (j * 64 >= Kh) break;            // wave-uniform
        int kk = j * 64 + lane;
        bool ok = kk < Kh;
        int idx = ok ? irow[kk] : 0;
        sid[j] = idx;
        const uint4* krow = (const uint4*)(qkv + (size_t)idx * 1536 + 512 + hh * 64);
        float d0 = 0.f, d1 = 0.f;
#pragma unroll
        for (int c = 0; c < 8; c++) {
            uint4 kv = krow[c];
            uint4 qv = q4p[c];
            d0 = dot2bf(kv.x, qv.x, d0);
            d1 = dot2bf(kv.y, qv.y, d1);
            d0 = dot2bf(kv.z, qv.z, d0);
            d1 = dot2bf(kv.w, qv.w, d1);
        }
        float dot = d0 + d1;
        float knv = kn[idx * NHEAD + hh];
        float dd = drow[ok ? kk : 0];
        float dec = expf(-sp * dd) + 1e-6f;
        float s = (dot - 0.5f * (qn2 + knv)) * 0.125f + logf(dec);
        sc[j] = ok ? s : -1e30f;
    }

    // ---- Phase B: softmax in registers ----
    float mx = fmaxf(fmaxf(sc[0], sc[1]), sc[2]);
    mx = wmax(mx);
    float se = 0.f;
#pragma unroll
    for (int j = 0; j < 3; j++) {
        float e = (sc[j] > -1e29f) ? expf(sc[j] - mx) : 0.f;
        sc[j] = e;
        se += e;
    }
    se = wsum(se);
    float inv = 1.f / se;

#pragma unroll
    for (int j = 0; j < 3; j++) {
        int kk = j * 64 + lane;
        if (kk < Kh) {
            asc[wid][kk] = sc[j] * inv;
            sidx[wid][kk] = sid[j];
        }
    }

    // ---- Phase C: PV packed. lane = (neighbor-of-pair, dim-pair); 16 neighbors/iter --
    int half = lane >> 5;
    int dp = lane & 31;
    const unsigned* vb = (const unsigned*)(qkv + 1024 + hh * 64) + dp;
    float ax = 0.f, ay = 0.f;
    for (int k0 = 0; k0 < Kh; k0 += 16) {
        float aa[8];
        unsigned vv[8];
        int ii[8];
#pragma unroll
        for (int u = 0; u < 8; u++) {
            int kk = k0 + 2 * u + half;
            ii[u] = sidx[wid][kk];
            aa[u] = asc[wid][kk];
        }
#pragma unroll
        for (int u = 0; u < 8; u++) vv[u] = vb[(size_t)ii[u] * 768];
#pragma unroll
        for (int u = 0; u < 8; u++) {
            ax += aa[u] * b2f((unsigned short)(vv[u] & 0xFFFF));
            ay += aa[u] * b2f((unsigned short)(vv[u] >> 16));
        }
    }
    ax += __shfl_xor(ax, 32, 64);
    ay += __shfl_xor(ay, 32, 64);
    if (lane < 32) {
        unsigned o = ((unsigned)f2b(ay) << 16) | (unsigned)f2b(ax);
        *((unsigned*)(xo + (size_t)n * DMODEL + hh * 64) + dp) = o;
    }
}

// ---------------- column partial sums ----------------
__global__ __launch_bounds__(512) void colpart_k(const float* __restrict__ Y, float* __restrict__ part)
{
    int c = threadIdx.x;
    int blk = blockIdx.x;
    const float* p = Y + (size_t)blk * 16 * DMODEL + c;
    float s = 0.f;
#pragma unroll
    for (int r = 0; r < 16; r++) s += p[r * DMODEL];
    part[blk * DMODEL + c] = s;
}

// ---------------- finish mean + head GEMV ----------------
__global__ __launch_bounds__(512) void finhead_k(
    const float* __restrict__ part, const float* __restrict__ head_w,
    const float* __restrict__ head_b, float* __restrict__ out)
{
    __shared__ float mv[DMODEL];
    int c = threadIdx.x;
    float s = 0.f;
    for (int i = 0; i < 256; i++) s += part[i * DMODEL + c];
    mv[c] = s * (1.f / NTOK);
    __syncthreads();
    if (c < 64) {
        float a0 = 0.f, a1 = 0.f;
        for (int d = c; d < DMODEL; d += 64) {
            float m = mv[d];
            a0 += m * head_w[d * NCLS + 0];
            a1 += m * head_w[d * NCLS + 1];
        }
        a0 = wsum(a0);
        a1 = wsum(a1);
        if (c == 0) { out[0] = a0 + head_b[0]; out[1] = a1 + head_b[1]; }
    }
}

extern "C" void kernel_launch(void* const* d_in, const int* in_sizes, int n_in,
                              void* d_out, int out_size, void* d_ws, size_t ws_size,
                              hipStream_t stream)
{
    const float* x        = (const float*)d_in[0];
    const float* distance = (const float*)d_in[1];
    const int*   indices  = (const int*)d_in[2];
    const float* adapter_w = (const float*)d_in[5];
    const float* adapter_b = (const float*)d_in[6];
    const float* res_w     = (const float*)d_in[7];
    const float* res_b     = (const float*)d_in[8];
    const float* ln1_g     = (const float*)d_in[9];
    const float* ln1_b     = (const float*)d_in[10];
    const float* qkv_w     = (const float*)d_in[11];
    const float* qkv_b     = (const float*)d_in[12];
    const float* proj_w    = (const float*)d_in[13];
    const float* proj_b    = (const float*)d_in[14];
    const float* ln2_g     = (const float*)d_in[15];
    const float* ln2_b     = (const float*)d_in[16];
    const float* fc1_w     = (const float*)d_in[17];
    const float* fc1_b     = (const float*)d_in[18];
    const float* fc2_w     = (const float*)d_in[19];
    const float* fc2_b     = (const float*)d_in[20];
    const float* lam       = (const float*)d_in[21];
    const float* lnf_g     = (const float*)d_in[22];
    const float* lnf_b     = (const float*)d_in[23];
    const float* head_w    = (const float*)d_in[24];
    const float* head_b    = (const float*)d_in[25];
    float* out = (float*)d_out;

    char* wsb = (char*)d_ws;
    float* h   = (float*)(wsb);                         // 8 MB
    float* h0  = (float*)(wsb + (8u << 20));            // 8 MB; dead during layers -> dsel
    float* dsel = (float*)(wsb + (8u << 20));           // 2.6 MB
    char* shared = wsb + (16u << 20);                   // 24 MB shared region
    unsigned short* xb    = (unsigned short*)shared;                // 8 MB (dead after adapter)
    unsigned short* qkvbb = (unsigned short*)shared;                // 12 MB bf16
    unsigned short* fc1b  = (unsigned short*)shared;                // 16 MB (after attn)
    unsigned short* adapter_wt = (unsigned short*)(shared + (8u << 20));  // 1 MB
    unsigned short* res_wt     = (unsigned short*)(shared + (9u << 20));  // 0.5 MB
    unsigned short* lnb  = (unsigned short*)(wsb + (40u << 20));    // 4 MB (also h0b)
    unsigned short* h0b  = lnb;
    unsigned short* xob  = (unsigned short*)(wsb + (44u << 20));    // 4 MB
    unsigned short* qkv_wt = (unsigned short*)(wsb + (48u << 20));  // 3 MB
    unsigned short* proj_wt = (unsigned short*)(wsb + (51u << 20)); // 1 MB
    unsigned short* fc1_wt  = (unsigned short*)(wsb + (52u << 20)); // 4 MB
    unsigned short* fc2_wt  = (unsigned short*)(wsb + (56u << 20)); // 4 MB
    float* kn   = (float*)(wsb + (60u << 20));                      // 128 KB
    float* part = (float*)(wsb + (60u << 20) + (1u << 18));         // 512 KB

    dim3 blk(256);

    // --- conversions (batched over layers via z) ---
    xcvt_k<<<(NTOK * EMB) / 2048, blk, 0, stream>>>(x, xb);
    wcvt_k<<<dim3(EMB / 64, DMODEL / 64, 1), blk, 0, stream>>>(adapter_w, adapter_wt, EMB, DMODEL);
    wcvt_k<<<dim3(DMODEL / 64, DMODEL / 64, 1), blk, 0, stream>>>(res_w, res_wt, DMODEL, DMODEL);
    wcvt_k<<<dim3(DMODEL / 64, 1536 / 64, NLAYER), blk, 0, stream>>>(qkv_w, qkv_wt, DMODEL, 1536);
    wcvt_k<<<dim3(DMODEL / 64, DMODEL / 64, NLAYER), blk, 0, stream>>>(proj_w, proj_wt, DMODEL, DMODEL);
    wcvt_k<<<dim3(DMODEL / 64, 2048 / 64, NLAYER), blk, 0, stream>>>(fc1_w, fc1_wt, DMODEL, 2048);
    wcvt_k<<<dim3(2048 / 64, DMODEL / 64, NLAYER), blk, 0, stream>>>(fc2_w, fc2_wt, 2048, DMODEL);

    // --- adapter: h0 = x @ adapter_w + b ---
    mgemm_k<64, 64, 2, 2, 4><<<dim3(NTOK / 64, DMODEL / 64), blk, 0, stream>>>(
        xb, adapter_wt, adapter_b, nullptr, h0, h0b, NTOK, DMODEL, EMB);
    // --- h = h0 + relu(h0 @ res_w + b) ---
    mgemm_k<64, 64, 2, 2, 1><<<dim3(NTOK / 64, DMODEL / 64), blk, 0, stream>>>(
        h0b, res_wt, res_b, h0, h, nullptr, NTOK, DMODEL, DMODEL);

    // dsel: h0 now dead until lnf
    dsel_k<<<NTOK, blk, 0, stream>>>(distance, indices, dsel);

    for (int l = 0; l < NLAYER; l++) {
        ln_k<1><<<NTOK, blk, 0, stream>>>(h, ln1_g + l * DMODEL, ln1_b + l * DMODEL, lnb, 1e-5f);
        mgemm_k<64, 128, 2, 2, 5><<<dim3(NTOK / 64, 1536 / 128), blk, 0, stream>>>(
            lnb, qkv_wt + (size_t)l * 1536 * DMODEL, qkv_b + l * 1536, nullptr,
            nullptr, qkvbb, NTOK, 1536, DMODEL);
        knb_k<<<NTOK, 512, 0, stream>>>(qkvbb, kn);
        attn_k<<<ATTN_BLOCKS, blk, 0, stream>>>(qkvbb, kn, indices, dsel, lam, xob, l);
        mgemm_k<64, 64, 2, 2, 3><<<dim3(NTOK / 64, DMODEL / 64), blk, 0, stream>>>(
            xob, proj_wt + (size_t)l * DMODEL * DMODEL, proj_b + l * DMODEL, h,
            h, nullptr, NTOK, DMODEL, DMODEL);
        ln_k<1><<<NTOK, blk, 0, stream>>>(h, ln2_g + l * DMODEL, ln2_b + l * DMODEL, lnb, 1e-5f);
        mgemm_k<64, 128, 2, 2, 2><<<dim3(NTOK / 64, 2048 / 128), blk, 0, stream>>>(
            lnb, fc1_wt + (size_t)l * 2048 * DMODEL, fc1_b + l * 2048, nullptr,
            nullptr, fc1b, NTOK, 2048, DMODEL);
        mgemm_k<64, 64, 2, 2, 3><<<dim3(NTOK / 64, DMODEL / 64), blk, 0, stream>>>(
            fc1b, fc2_wt + (size_t)l * DMODEL * 2048, fc2_b + l * DMODEL, h,
            h, nullptr, NTOK, DMODEL, 2048);
    }

    ln_k<0><<<NTOK, blk, 0, stream>>>(h, lnf_g, lnf_b, h0, 1e-6f);
    colpart_k<<<256, 512, 0, stream>>>(h0, part);
    finhead_k<<<1, 512, 0, stream>>>(part, head_w, head_b, out);
}

// Round 8
// 442.070 us; speedup vs baseline: 1.1008x; 1.1008x over previous
//
#include <hip/hip_runtime.h>
#include <hip/hip_bf16.h>

#define NTOK 4096
#define EMB 1024
#define DMODEL 512
#define NHEAD 8
#define NLAYER 2
#define NCLS 2
#define KMAX 160

typedef __attribute__((ext_vector_type(8))) short bf16x8;
typedef __attribute__((ext_vector_type(4))) float f32x4;

__device__ inline unsigned short f2b(float f) {
    unsigned u = __float_as_uint(f);
    u = u + 0x7FFFu + ((u >> 16) & 1u);
    return (unsigned short)(u >> 16);
}
__device__ inline float b2f(unsigned short s) {
    return __uint_as_float((unsigned)s << 16);
}

__device__ inline float wsum(float v) {
    for (int o = 32; o > 0; o >>= 1) v += __shfl_xor(v, o, 64);
    return v;
}
__device__ inline float wmax(float v) {
    for (int o = 32; o > 0; o >>= 1) v = fmaxf(v, __shfl_xor(v, o, 64));
    return v;
}

// async global->LDS, 16 B per lane. dest must be wave-uniform base + lane*16.
typedef __attribute__((address_space(3))) unsigned lds_u32_t;
typedef __attribute__((address_space(1))) const unsigned glb_u32_t;
__device__ inline void gload16(const void* g, void* l) {
    __builtin_amdgcn_global_load_lds((glb_u32_t*)(unsigned long long)g,
                                     (lds_u32_t*)(unsigned)(unsigned long long)l,
                                     16, 0, 0);
}

// Balanced head->XCD schedule: work blocks of 4 rows, 1024 blocks/head.
__device__ const int g_s0cnt[8]  = {576, 448, 720, 144, 365, 490, 460, 159};
__device__ const int g_s0h[8]    = {7, 7, 6, 6, 5, 4, 3, 2};
__device__ const int g_s0base[8] = {0, 576, 160, 880, 659, 534, 564, 865};
__device__ const int g_s1cnt[8]  = {0, 160, 0, 659, 534, 564, 865, 1024};
__device__ const int g_s1h[8]    = {0, 6, 0, 5, 4, 3, 2, 1};
#define ATTN_BLOCKS (2207 * 8)

// ---------------- weight convert+transpose: W[K][N] f32 -> Wt[N][K] bf16 (z = layer) ---
__global__ __launch_bounds__(256) void wcvt_k(const float* __restrict__ W,
                                              unsigned short* __restrict__ Wt,
                                              int K, int N)
{
    __shared__ unsigned short tile[64][72];
    size_t ls = (size_t)K * N * blockIdx.z;
    const float* Wl = W + ls;
    unsigned short* Wtl = Wt + ls;
    int k0 = blockIdx.x * 64, n0 = blockIdx.y * 64;
    int t = threadIdx.x;
    int kl = t >> 2, nb = (t & 3) * 16;
    const float* src = Wl + (size_t)(k0 + kl) * N + n0 + nb;
#pragma unroll
    for (int i = 0; i < 4; i++) {
        float4 v = *(const float4*)(src + 4 * i);
        tile[nb + 4 * i + 0][kl] = f2b(v.x);
        tile[nb + 4 * i + 1][kl] = f2b(v.y);
        tile[nb + 4 * i + 2][kl] = f2b(v.z);
        tile[nb + 4 * i + 3][kl] = f2b(v.w);
    }
    __syncthreads();
    int nl = t >> 2, ks = (t & 3) * 16;
    unsigned short* dst = Wtl + (size_t)(n0 + nl) * K + k0 + ks;
    *(uint4*)dst = *(const uint4*)&tile[nl][ks];
    *(uint4*)(dst + 8) = *(const uint4*)&tile[nl][ks + 8];
}

// ---------------- x f32 -> bf16 flat ----------------
__global__ __launch_bounds__(256) void xcvt_k(const float* __restrict__ X,
                                              unsigned short* __restrict__ Xb)
{
    int i = (blockIdx.x * 256 + threadIdx.x) * 8;
    float4 a = *(const float4*)(X + i);
    float4 b = *(const float4*)(X + i + 4);
    unsigned short o[8];
    o[0] = f2b(a.x); o[1] = f2b(a.y); o[2] = f2b(a.z); o[3] = f2b(a.w);
    o[4] = f2b(b.x); o[5] = f2b(b.y); o[6] = f2b(b.z); o[7] = f2b(b.w);
    *(uint4*)(Xb + i) = *(const uint4*)o;
}

// ---------------- dsel[n][k] = distance[n][indices[n][k]] ----------------
__global__ __launch_bounds__(256) void dsel_k(const float* __restrict__ distance,
                                              const int* __restrict__ indices,
                                              float* __restrict__ dsel)
{
    int n = blockIdx.x, t = threadIdx.x;
    if (t < KMAX) {
        int idx = indices[(size_t)n * KMAX + t];
        dsel[(size_t)n * KMAX + t] = distance[(size_t)n * NTOK + idx];
    }
}

// ---------------- kn[n][h] = sum_d K[n,h,d]^2 from bf16 qkv ----------------
__global__ __launch_bounds__(512) void knb_k(const unsigned short* __restrict__ qkv,
                                             float* __restrict__ kn)
{
    int n = blockIdx.x;
    int hh = threadIdx.x >> 6, lane = threadIdx.x & 63;
    float kv = b2f(qkv[(size_t)n * 1536 + 512 + hh * 64 + lane]);
    float ks = wsum(kv * kv);
    if (lane == 0) kn[n * NHEAD + hh] = ks;
}

// ---------------- MFMA GEMM (m97 structure): C = epi(A_bf16[M,K] @ Wt[N,K]^T + bias) --
template <int BM, int BN, int WM, int WN, int MODE>
__global__ __launch_bounds__(256) void mgemm_k(
    const unsigned short* __restrict__ A, const unsigned short* __restrict__ Wt,
    const float* __restrict__ bias, const float* __restrict__ resid,
    float* __restrict__ Cf, unsigned short* __restrict__ Cb,
    int M, int N, int K)
{
    constexpr int SM = BM / WM;
    constexpr int SN = BN / WN;
    constexpr int MR = SM / 16;
    constexpr int NR = SN / 16;

    __shared__ unsigned short Asl[BM * 32];
    __shared__ unsigned short Bsl[BN * 32];

    int tid = threadIdx.x;
    int bm = blockIdx.x * BM, bn = blockIdx.y * BN;
    int lane = tid & 63, wid = tid >> 6;
    int wm = wid / WN, wn = wid % WN;
    int l15 = lane & 15, l4 = lane >> 4;

    f32x4 acc[MR][NR] = {};

    int sr = tid >> 2, sc = (tid & 3) * 8;
    const unsigned short* Asrc = A  + (size_t)(bm + sr) * K + sc;
    const unsigned short* Bsrc = Wt + (size_t)(bn + sr) * K + sc;
    unsigned short* Adst = &Asl[sr * 32 + sc];
    unsigned short* Bdst = &Bsl[sr * 32 + sc];

    int arow0 = (wm * SM + l15) * 32 + l4 * 8;
    int brow0 = (wn * SN + l15) * 32 + l4 * 8;

    for (int k0 = 0; k0 < K; k0 += 32) {
#pragma unroll
        for (int i = 0; i < BM / 64; i++)
            gload16(Asrc + (size_t)(i * 64) * K + k0, Adst + i * 64 * 32);
#pragma unroll
        for (int i = 0; i < BN / 64; i++)
            gload16(Bsrc + (size_t)(i * 64) * K + k0, Bdst + i * 64 * 32);
        __syncthreads();

        bf16x8 af[MR], bfr[NR];
#pragma unroll
        for (int mr = 0; mr < MR; mr++) af[mr] = *(const bf16x8*)&Asl[arow0 + mr * 16 * 32];
#pragma unroll
        for (int nr = 0; nr < NR; nr++) bfr[nr] = *(const bf16x8*)&Bsl[brow0 + nr * 16 * 32];
#pragma unroll
        for (int mr = 0; mr < MR; mr++)
#pragma unroll
            for (int nr = 0; nr < NR; nr++)
                acc[mr][nr] = __builtin_amdgcn_mfma_f32_16x16x32_bf16(af[mr], bfr[nr], acc[mr][nr], 0, 0, 0);
        __syncthreads();
    }

#pragma unroll
    for (int mr = 0; mr < MR; mr++) {
#pragma unroll
        for (int nr = 0; nr < NR; nr++) {
            int col = bn + wn * SN + nr * 16 + l15;
            float bcol = bias[col];
#pragma unroll
            for (int r = 0; r < 4; r++) {
                int row = bm + wm * SM + mr * 16 + l4 * 4 + r;
                size_t off = (size_t)row * N + col;
                float v = acc[mr][nr][r] + bcol;
                if (MODE == 0) {
                    Cf[off] = v;
                } else if (MODE == 1) {
                    Cf[off] = resid[off] + fmaxf(v, 0.f);
                } else if (MODE == 2) {
                    float t3 = tanhf(0.7978845608028654f * (v + 0.044715f * v * v * v));
                    Cb[off] = f2b(0.5f * v * (1.f + t3));
                } else if (MODE == 3) {
                    Cf[off] = resid[off] + v;
                } else if (MODE == 4) {
                    Cf[off] = v;
                    Cb[off] = f2b(v);
                } else {
                    Cb[off] = f2b(v);
                }
            }
        }
    }
}

// ---------------- LayerNorm over D=512, one row per block ----------------
template <int OUTB>
__global__ __launch_bounds__(256) void ln_k(
    const float* __restrict__ X, const float* __restrict__ g,
    const float* __restrict__ bta, void* __restrict__ Yv, float eps)
{
    int row = blockIdx.x;
    int tid = threadIdx.x;
    const float* xr = X + (size_t)row * DMODEL;
    float v0 = xr[tid], v1 = xr[tid + 256];
    __shared__ float red[8];
    float s = wsum(v0 + v1);
    int wid = tid >> 6, lane = tid & 63;
    if (lane == 0) red[wid] = s;
    __syncthreads();
    float m = (red[0] + red[1] + red[2] + red[3]) * (1.f / DMODEL);
    float d0 = v0 - m, d1 = v1 - m;
    float sq = wsum(d0 * d0 + d1 * d1);
    if (lane == 0) red[4 + wid] = sq;
    __syncthreads();
    float var = (red[4] + red[5] + red[6] + red[7]) * (1.f / DMODEL);
    float rs = 1.0f / sqrtf(var + eps);
    float y0 = d0 * rs * g[tid] + bta[tid];
    float y1 = d1 * rs * g[tid + 256] + bta[tid + 256];
    if (OUTB) {
        unsigned short* Y = (unsigned short*)Yv;
        Y[(size_t)row * DMODEL + tid] = f2b(y0);
        Y[(size_t)row * DMODEL + tid + 256] = f2b(y1);
    } else {
        float* Y = (float*)Yv;
        Y[(size_t)row * DMODEL + tid] = y0;
        Y[(size_t)row * DMODEL + tid + 256] = y1;
    }
}

// ---------------- gathered attention, bf16 qkv, balanced head->XCD schedule --------
__global__ __launch_bounds__(256) void attn_k(
    const unsigned short* __restrict__ qkv,   // [n][1536] bf16
    const float* __restrict__ kn,             // [n][8]
    const int* __restrict__ indices, const float* __restrict__ dsel,
    const float* __restrict__ lam, unsigned short* __restrict__ xo, int layer)
{
    int xcd = blockIdx.x & 7;
    int t = blockIdx.x >> 3;
    int hh, blk;
    int c0 = g_s0cnt[xcd];
    if (t < c0) {
        hh = g_s0h[xcd]; blk = g_s0base[xcd] + t;
    } else {
        t -= c0;
        int c1 = g_s1cnt[xcd];
        if (t < c1) {
            hh = g_s1h[xcd]; blk = t;
        } else if (xcd == 7 && t - c1 < 1024) {
            hh = 0; blk = t - c1;
        } else {
            return;
        }
    }

    int wid = threadIdx.x >> 6, lane = threadIdx.x & 63;
    int n = blk * 4 + wid;
    int Kh = 32 + 16 * hh + (hh == 7 ? 16 : 0);   // 32..160, multiples of 16

    __shared__ __align__(16) float qs[4][64];
    __shared__ float asc[4][KMAX];
    __shared__ int   sidx[4][KMAX];

    float qd = b2f(qkv[(size_t)n * 1536 + hh * 64 + lane]);
    qs[wid][lane] = qd;
    float qn2 = wsum(qd * qd);
    float sp = log1pf(expf(lam[layer * NHEAD + hh]));

    const int* irow = indices + (size_t)n * KMAX;
    const float* drow = dsel + (size_t)n * KMAX;

    // ---- Phase A: scores (FMA form), lane = neighbor ----
    float sc[3];
    int   sid[3];
#pragma unroll
    for (int j = 0; j < 3; j++) { sc[j] = -1e30f; sid[j] = 0; }

    const float4* q4 = (const float4*)&qs[wid][0];
#pragma unroll
    for (int j = 0; j < 3; j++) {
        if (j * 64 >= Kh) break;            // wave-uniform
        int kk = j * 64 + lane;
        bool ok = kk < Kh;
        int idx = ok ? irow[kk] : 0;
        sid[j] = idx;
        const uint4* krow = (const uint4*)(qkv + (size_t)idx * 1536 + 512 + hh * 64);
        float dot = 0.f;
#pragma unroll
        for (int c = 0; c < 8; c++) {
            uint4 kv = krow[c];
            const unsigned short* kp = (const unsigned short*)&kv;
            float4 qa = q4[c * 2], qb = q4[c * 2 + 1];
            dot += qa.x * b2f(kp[0]) + qa.y * b2f(kp[1]) + qa.z * b2f(kp[2]) + qa.w * b2f(kp[3])
                 + qb.x * b2f(kp[4]) + qb.y * b2f(kp[5]) + qb.z * b2f(kp[6]) + qb.w * b2f(kp[7]);
        }
        float knv = kn[idx * NHEAD + hh];
        float dd = drow[ok ? kk : 0];
        float dec = expf(-sp * dd) + 1e-6f;
        float s = (dot - 0.5f * (qn2 + knv)) * 0.125f + logf(dec);
        sc[j] = ok ? s : -1e30f;
    }

    // ---- Phase B: softmax in registers ----
    float mx = fmaxf(fmaxf(sc[0], sc[1]), sc[2]);
    mx = wmax(mx);
    float se = 0.f;
#pragma unroll
    for (int j = 0; j < 3; j++) {
        float e = (sc[j] > -1e29f) ? expf(sc[j] - mx) : 0.f;
        sc[j] = e;
        se += e;
    }
    se = wsum(se);
    float inv = 1.f / se;

#pragma unroll
    for (int j = 0; j < 3; j++) {
        int kk = j * 64 + lane;
        if (kk < Kh) {
            asc[wid][kk] = sc[j] * inv;
            sidx[wid][kk] = sid[j];
        }
    }

    // ---- Phase C: PV, 8 lanes per neighbor (lane = g*8+q), uint4 V loads ----
    // lane loads V dims q*8..q*8+7 (16 B) of neighbor group g; 32 neighbors in flight.
    int g = lane >> 3, q = lane & 7;
    const uint4* vb = (const uint4*)(qkv + 1024 + hh * 64 + q * 8);  // +idx*192 per row
    float a8[8] = {};
    int k0 = 0;
    int kmain = Kh & ~31;
    for (; k0 < kmain; k0 += 32) {
        int ii[4]; float aa[4]; uint4 vv[4];
#pragma unroll
        for (int u = 0; u < 4; u++) {
            int kk = k0 + u * 8 + g;
            ii[u] = sidx[wid][kk];
            aa[u] = asc[wid][kk];
        }
#pragma unroll
        for (int u = 0; u < 4; u++) vv[u] = vb[(size_t)ii[u] * 192];
#pragma unroll
        for (int u = 0; u < 4; u++) {
            const unsigned short* vp = (const unsigned short*)&vv[u];
#pragma unroll
            for (int d = 0; d < 8; d++) a8[d] += aa[u] * b2f(vp[d]);
        }
    }
    if (Kh & 16) {
        int ii[2]; float aa[2]; uint4 vv[2];
#pragma unroll
        for (int u = 0; u < 2; u++) {
            int kk = k0 + u * 8 + g;
            ii[u] = sidx[wid][kk];
            aa[u] = asc[wid][kk];
        }
#pragma unroll
        for (int u = 0; u < 2; u++) vv[u] = vb[(size_t)ii[u] * 192];
#pragma unroll
        for (int u = 0; u < 2; u++) {
            const unsigned short* vp = (const unsigned short*)&vv[u];
#pragma unroll
            for (int d = 0; d < 8; d++) a8[d] += aa[u] * b2f(vp[d]);
        }
    }
#pragma unroll
    for (int d = 0; d < 8; d++) {
        a8[d] += __shfl_xor(a8[d], 8, 64);
        a8[d] += __shfl_xor(a8[d], 16, 64);
        a8[d] += __shfl_xor(a8[d], 32, 64);
    }
    if (lane < 8) {
        unsigned o[4];
#pragma unroll
        for (int p = 0; p < 4; p++)
            o[p] = ((unsigned)f2b(a8[2 * p + 1]) << 16) | (unsigned)f2b(a8[2 * p]);
        *(uint4*)(xo + (size_t)n * DMODEL + hh * 64 + lane * 8) = *(uint4*)o;
    }
}

// ---------------- column partial sums ----------------
__global__ __launch_bounds__(512) void colpart_k(const float* __restrict__ Y, float* __restrict__ part)
{
    int c = threadIdx.x;
    int blk = blockIdx.x;
    const float* p = Y + (size_t)blk * 16 * DMODEL + c;
    float s = 0.f;
#pragma unroll
    for (int r = 0; r < 16; r++) s += p[r * DMODEL];
    part[blk * DMODEL + c] = s;
}

// ---------------- finish mean + head GEMV ----------------
__global__ __launch_bounds__(512) void finhead_k(
    const float* __restrict__ part, const float* __restrict__ head_w,
    const float* __restrict__ head_b, float* __restrict__ out)
{
    __shared__ float mv[DMODEL];
    int c = threadIdx.x;
    float s = 0.f;
    for (int i = 0; i < 256; i++) s += part[i * DMODEL + c];
    mv[c] = s * (1.f / NTOK);
    __syncthreads();
    if (c < 64) {
        float a0 = 0.f, a1 = 0.f;
        for (int d = c; d < DMODEL; d += 64) {
            float m = mv[d];
            a0 += m * head_w[d * NCLS + 0];
            a1 += m * head_w[d * NCLS + 1];
        }
        a0 = wsum(a0);
        a1 = wsum(a1);
        if (c == 0) { out[0] = a0 + head_b[0]; out[1] = a1 + head_b[1]; }
    }
}

extern "C" void kernel_launch(void* const* d_in, const int* in_sizes, int n_in,
                              void* d_out, int out_size, void* d_ws, size_t ws_size,
                              hipStream_t stream)
{
    const float* x        = (const float*)d_in[0];
    const float* distance = (const float*)d_in[1];
    const int*   indices  = (const int*)d_in[2];
    const float* adapter_w = (const float*)d_in[5];
    const float* adapter_b = (const float*)d_in[6];
    const float* res_w     = (const float*)d_in[7];
    const float* res_b     = (const float*)d_in[8];
    const float* ln1_g     = (const float*)d_in[9];
    const float* ln1_b     = (const float*)d_in[10];
    const float* qkv_w     = (const float*)d_in[11];
    const float* qkv_b     = (const float*)d_in[12];
    const float* proj_w    = (const float*)d_in[13];
    const float* proj_b    = (const float*)d_in[14];
    const float* ln2_g     = (const float*)d_in[15];
    const float* ln2_b     = (const float*)d_in[16];
    const float* fc1_w     = (const float*)d_in[17];
    const float* fc1_b     = (const float*)d_in[18];
    const float* fc2_w     = (const float*)d_in[19];
    const float* fc2_b     = (const float*)d_in[20];
    const float* lam       = (const float*)d_in[21];
    const float* lnf_g     = (const float*)d_in[22];
    const float* lnf_b     = (const float*)d_in[23];
    const float* head_w    = (const float*)d_in[24];
    const float* head_b    = (const float*)d_in[25];
    float* out = (float*)d_out;

    char* wsb = (char*)d_ws;
    float* h   = (float*)(wsb);                         // 8 MB
    float* h0  = (float*)(wsb + (8u << 20));            // 8 MB; dead during layers -> dsel
    float* dsel = (float*)(wsb + (8u << 20));           // 2.6 MB
    char* shared = wsb + (16u << 20);                   // 24 MB shared region
    unsigned short* xb    = (unsigned short*)shared;                // 8 MB (dead after adapter)
    unsigned short* qkvbb = (unsigned short*)shared;                // 12 MB bf16
    unsigned short* fc1b  = (unsigned short*)shared;                // 16 MB (after attn)
    unsigned short* adapter_wt = (unsigned short*)(shared + (8u << 20));  // 1 MB
    unsigned short* res_wt     = (unsigned short*)(shared + (9u << 20));  // 0.5 MB
    unsigned short* lnb  = (unsigned short*)(wsb + (40u << 20));    // 4 MB (also h0b)
    unsigned short* h0b  = lnb;
    unsigned short* xob  = (unsigned short*)(wsb + (44u << 20));    // 4 MB
    unsigned short* qkv_wt = (unsigned short*)(wsb + (48u << 20));  // 3 MB
    unsigned short* proj_wt = (unsigned short*)(wsb + (51u << 20)); // 1 MB
    unsigned short* fc1_wt  = (unsigned short*)(wsb + (52u << 20)); // 4 MB
    unsigned short* fc2_wt  = (unsigned short*)(wsb + (56u << 20)); // 4 MB
    float* kn   = (float*)(wsb + (60u << 20));                      // 128 KB
    float* part = (float*)(wsb + (60u << 20) + (1u << 18));         // 512 KB

    dim3 blk(256);

    // --- conversions (batched over layers via z) ---
    xcvt_k<<<(NTOK * EMB) / 2048, blk, 0, stream>>>(x, xb);
    wcvt_k<<<dim3(EMB / 64, DMODEL / 64, 1), blk, 0, stream>>>(adapter_w, adapter_wt, EMB, DMODEL);
    wcvt_k<<<dim3(DMODEL / 64, DMODEL / 64, 1), blk, 0, stream>>>(res_w, res_wt, DMODEL, DMODEL);
    wcvt_k<<<dim3(DMODEL / 64, 1536 / 64, NLAYER), blk, 0, stream>>>(qkv_w, qkv_wt, DMODEL, 1536);
    wcvt_k<<<dim3(DMODEL / 64, DMODEL / 64, NLAYER), blk, 0, stream>>>(proj_w, proj_wt, DMODEL, DMODEL);
    wcvt_k<<<dim3(DMODEL / 64, 2048 / 64, NLAYER), blk, 0, stream>>>(fc1_w, fc1_wt, DMODEL, 2048);
    wcvt_k<<<dim3(2048 / 64, DMODEL / 64, NLAYER), blk, 0, stream>>>(fc2_w, fc2_wt, 2048, DMODEL);

    // --- adapter: h0 = x @ adapter_w + b ---
    mgemm_k<64, 64, 2, 2, 4><<<dim3(NTOK / 64, DMODEL / 64), blk, 0, stream>>>(
        xb, adapter_wt, adapter_b, nullptr, h0, h0b, NTOK, DMODEL, EMB);
    // --- h = h0 + relu(h0 @ res_w + b) ---
    mgemm_k<64, 64, 2, 2, 1><<<dim3(NTOK / 64, DMODEL / 64), blk, 0, stream>>>(
        h0b, res_wt, res_b, h0, h, nullptr, NTOK, DMODEL, DMODEL);

    // dsel: h0 now dead until lnf
    dsel_k<<<NTOK, blk, 0, stream>>>(distance, indices, dsel);

    for (int l = 0; l < NLAYER; l++) {
        ln_k<1><<<NTOK, blk, 0, stream>>>(h, ln1_g + l * DMODEL, ln1_b + l * DMODEL, lnb, 1e-5f);
        mgemm_k<64, 128, 2, 2, 5><<<dim3(NTOK / 64, 1536 / 128), blk, 0, stream>>>(
            lnb, qkv_wt + (size_t)l * 1536 * DMODEL, qkv_b + l * 1536, nullptr,
            nullptr, qkvbb, NTOK, 1536, DMODEL);
        knb_k<<<NTOK, 512, 0, stream>>>(qkvbb, kn);
        attn_k<<<ATTN_BLOCKS, blk, 0, stream>>>(qkvbb, kn, indices, dsel, lam, xob, l);
        mgemm_k<64, 64, 2, 2, 3><<<dim3(NTOK / 64, DMODEL / 64), blk, 0, stream>>>(
            xob, proj_wt + (size_t)l * DMODEL * DMODEL, proj_b + l * DMODEL, h,
            h, nullptr, NTOK, DMODEL, DMODEL);
        ln_k<1><<<NTOK, blk, 0, stream>>>(h, ln2_g + l * DMODEL, ln2_b + l * DMODEL, lnb, 1e-5f);
        mgemm_k<64, 128, 2, 2, 2><<<dim3(NTOK / 64, 2048 / 128), blk, 0, stream>>>(
            lnb, fc1_wt + (size_t)l * 2048 * DMODEL, fc1_b + l * 2048, nullptr,
            nullptr, fc1b, NTOK, 2048, DMODEL);
        mgemm_k<64, 64, 2, 2, 3><<<dim3(NTOK / 64, DMODEL / 64), blk, 0, stream>>>(
            fc1b, fc2_wt + (size_t)l * DMODEL * 2048, fc2_b + l * DMODEL, h,
            h, nullptr, NTOK, DMODEL, 2048);
    }

    ln_k<0><<<NTOK, blk, 0, stream>>>(h, lnf_g, lnf_b, h0, 1e-6f);
    colpart_k<<<256, 512, 0, stream>>>(h0, part);
    finhead_k<<<1, 512, 0, stream>>>(part, head_w, head_b, out);
}

// Round 9
// 385.312 us; speedup vs baseline: 1.2629x; 1.1473x over previous
//
#include <hip/hip_runtime.h>
#include <hip/hip_bf16.h>

#define NTOK 4096
#define EMB 1024
#define DMODEL 512
#define NHEAD 8
#define NLAYER 2
#define NCLS 2
#define KMAX 160

typedef __attribute__((ext_vector_type(8))) short bf16x8;
typedef __attribute__((ext_vector_type(4))) float f32x4;

__device__ inline unsigned short f2b(float f) {
    unsigned u = __float_as_uint(f);
    u = u + 0x7FFFu + ((u >> 16) & 1u);
    return (unsigned short)(u >> 16);
}
__device__ inline float b2f(unsigned short s) {
    return __uint_as_float((unsigned)s << 16);
}

__device__ inline float wsum(float v) {
    for (int o = 32; o > 0; o >>= 1) v += __shfl_xor(v, o, 64);
    return v;
}
__device__ inline float wmax(float v) {
    for (int o = 32; o > 0; o >>= 1) v = fmaxf(v, __shfl_xor(v, o, 64));
    return v;
}

// async global->LDS, 16 B per lane. dest must be wave-uniform base + lane*16.
typedef __attribute__((address_space(3))) unsigned lds_u32_t;
typedef __attribute__((address_space(1))) const unsigned glb_u32_t;
__device__ inline void gload16(const void* g, void* l) {
    __builtin_amdgcn_global_load_lds((glb_u32_t*)(unsigned long long)g,
                                     (lds_u32_t*)(unsigned)(unsigned long long)l,
                                     16, 0, 0);
}

// Balanced head->XCD schedule: work blocks of 4 rows, 1024 blocks/head.
__device__ const int g_s0cnt[8]  = {576, 448, 720, 144, 365, 490, 460, 159};
__device__ const int g_s0h[8]    = {7, 7, 6, 6, 5, 4, 3, 2};
__device__ const int g_s0base[8] = {0, 576, 160, 880, 659, 534, 564, 865};
__device__ const int g_s1cnt[8]  = {0, 160, 0, 659, 534, 564, 865, 1024};
__device__ const int g_s1h[8]    = {0, 6, 0, 5, 4, 3, 2, 1};
#define ATTN_BLOCKS (2207 * 8)

// ---------------- weight convert+transpose: W[K][N] f32 -> Wt[N][K] bf16 (z = layer) ---
__global__ __launch_bounds__(256) void wcvt_k(const float* __restrict__ W,
                                              unsigned short* __restrict__ Wt,
                                              int K, int N)
{
    __shared__ unsigned short tile[64][72];
    size_t ls = (size_t)K * N * blockIdx.z;
    const float* Wl = W + ls;
    unsigned short* Wtl = Wt + ls;
    int k0 = blockIdx.x * 64, n0 = blockIdx.y * 64;
    int t = threadIdx.x;
    int kl = t >> 2, nb = (t & 3) * 16;
    const float* src = Wl + (size_t)(k0 + kl) * N + n0 + nb;
#pragma unroll
    for (int i = 0; i < 4; i++) {
        float4 v = *(const float4*)(src + 4 * i);
        tile[nb + 4 * i + 0][kl] = f2b(v.x);
        tile[nb + 4 * i + 1][kl] = f2b(v.y);
        tile[nb + 4 * i + 2][kl] = f2b(v.z);
        tile[nb + 4 * i + 3][kl] = f2b(v.w);
    }
    __syncthreads();
    int nl = t >> 2, ks = (t & 3) * 16;
    unsigned short* dst = Wtl + (size_t)(n0 + nl) * K + k0 + ks;
    *(uint4*)dst = *(const uint4*)&tile[nl][ks];
    *(uint4*)(dst + 8) = *(const uint4*)&tile[nl][ks + 8];
}

// ---------------- x f32 -> bf16 flat ----------------
__global__ __launch_bounds__(256) void xcvt_k(const float* __restrict__ X,
                                              unsigned short* __restrict__ Xb)
{
    int i = (blockIdx.x * 256 + threadIdx.x) * 8;
    float4 a = *(const float4*)(X + i);
    float4 b = *(const float4*)(X + i + 4);
    unsigned short o[8];
    o[0] = f2b(a.x); o[1] = f2b(a.y); o[2] = f2b(a.z); o[3] = f2b(a.w);
    o[4] = f2b(b.x); o[5] = f2b(b.y); o[6] = f2b(b.z); o[7] = f2b(b.w);
    *(uint4*)(Xb + i) = *(const uint4*)o;
}

// ---------------- dsel[n][k] = distance[n][indices[n][k]] ----------------
__global__ __launch_bounds__(256) void dsel_k(const float* __restrict__ distance,
                                              const int* __restrict__ indices,
                                              float* __restrict__ dsel)
{
    int n = blockIdx.x, t = threadIdx.x;
    if (t < KMAX) {
        int idx = indices[(size_t)n * KMAX + t];
        dsel[(size_t)n * KMAX + t] = distance[(size_t)n * NTOK + idx];
    }
}

// ---------------- MFMA GEMM (m97 structure): C = epi(A_bf16[M,K] @ Wt[N,K]^T + bias) --
template <int BM, int BN, int WM, int WN, int MODE>
__global__ __launch_bounds__(256) void mgemm_k(
    const unsigned short* __restrict__ A, const unsigned short* __restrict__ Wt,
    const float* __restrict__ bias, const float* __restrict__ resid,
    float* __restrict__ Cf, unsigned short* __restrict__ Cb,
    int M, int N, int K)
{
    constexpr int SM = BM / WM;
    constexpr int SN = BN / WN;
    constexpr int MR = SM / 16;
    constexpr int NR = SN / 16;

    __shared__ unsigned short Asl[BM * 32];
    __shared__ unsigned short Bsl[BN * 32];

    int tid = threadIdx.x;
    int bm = blockIdx.x * BM, bn = blockIdx.y * BN;
    int lane = tid & 63, wid = tid >> 6;
    int wm = wid / WN, wn = wid % WN;
    int l15 = lane & 15, l4 = lane >> 4;

    f32x4 acc[MR][NR] = {};

    int sr = tid >> 2, sc = (tid & 3) * 8;
    const unsigned short* Asrc = A  + (size_t)(bm + sr) * K + sc;
    const unsigned short* Bsrc = Wt + (size_t)(bn + sr) * K + sc;
    unsigned short* Adst = &Asl[sr * 32 + sc];
    unsigned short* Bdst = &Bsl[sr * 32 + sc];

    int arow0 = (wm * SM + l15) * 32 + l4 * 8;
    int brow0 = (wn * SN + l15) * 32 + l4 * 8;

    for (int k0 = 0; k0 < K; k0 += 32) {
#pragma unroll
        for (int i = 0; i < BM / 64; i++)
            gload16(Asrc + (size_t)(i * 64) * K + k0, Adst + i * 64 * 32);
#pragma unroll
        for (int i = 0; i < BN / 64; i++)
            gload16(Bsrc + (size_t)(i * 64) * K + k0, Bdst + i * 64 * 32);
        __syncthreads();

        bf16x8 af[MR], bfr[NR];
#pragma unroll
        for (int mr = 0; mr < MR; mr++) af[mr] = *(const bf16x8*)&Asl[arow0 + mr * 16 * 32];
#pragma unroll
        for (int nr = 0; nr < NR; nr++) bfr[nr] = *(const bf16x8*)&Bsl[brow0 + nr * 16 * 32];
#pragma unroll
        for (int mr = 0; mr < MR; mr++)
#pragma unroll
            for (int nr = 0; nr < NR; nr++)
                acc[mr][nr] = __builtin_amdgcn_mfma_f32_16x16x32_bf16(af[mr], bfr[nr], acc[mr][nr], 0, 0, 0);
        __syncthreads();
    }

#pragma unroll
    for (int mr = 0; mr < MR; mr++) {
#pragma unroll
        for (int nr = 0; nr < NR; nr++) {
            int col = bn + wn * SN + nr * 16 + l15;
            float bcol = bias[col];
#pragma unroll
            for (int r = 0; r < 4; r++) {
                int row = bm + wm * SM + mr * 16 + l4 * 4 + r;
                size_t off = (size_t)row * N + col;
                float v = acc[mr][nr][r] + bcol;
                if (MODE == 0) {
                    Cf[off] = v;
                } else if (MODE == 1) {
                    Cf[off] = resid[off] + fmaxf(v, 0.f);
                } else if (MODE == 2) {
                    float t3 = tanhf(0.7978845608028654f * (v + 0.044715f * v * v * v));
                    Cb[off] = f2b(0.5f * v * (1.f + t3));
                } else if (MODE == 3) {
                    Cf[off] = resid[off] + v;
                } else if (MODE == 4) {
                    Cf[off] = v;
                    Cb[off] = f2b(v);
                } else {
                    Cb[off] = f2b(v);
                }
            }
        }
    }
}

// ---------------- LayerNorm over D=512, one row per block ----------------
template <int OUTB>
__global__ __launch_bounds__(256) void ln_k(
    const float* __restrict__ X, const float* __restrict__ g,
    const float* __restrict__ bta, void* __restrict__ Yv, float eps)
{
    int row = blockIdx.x;
    int tid = threadIdx.x;
    const float* xr = X + (size_t)row * DMODEL;
    float v0 = xr[tid], v1 = xr[tid + 256];
    __shared__ float red[8];
    float s = wsum(v0 + v1);
    int wid = tid >> 6, lane = tid & 63;
    if (lane == 0) red[wid] = s;
    __syncthreads();
    float m = (red[0] + red[1] + red[2] + red[3]) * (1.f / DMODEL);
    float d0 = v0 - m, d1 = v1 - m;
    float sq = wsum(d0 * d0 + d1 * d1);
    if (lane == 0) red[4 + wid] = sq;
    __syncthreads();
    float var = (red[4] + red[5] + red[6] + red[7]) * (1.f / DMODEL);
    float rs = 1.0f / sqrtf(var + eps);
    float y0 = d0 * rs * g[tid] + bta[tid];
    float y1 = d1 * rs * g[tid + 256] + bta[tid + 256];
    if (OUTB) {
        unsigned short* Y = (unsigned short*)Yv;
        Y[(size_t)row * DMODEL + tid] = f2b(y0);
        Y[(size_t)row * DMODEL + tid + 256] = f2b(y1);
    } else {
        float* Y = (float*)Yv;
        Y[(size_t)row * DMODEL + tid] = y0;
        Y[(size_t)row * DMODEL + tid + 256] = y1;
    }
}

// ---------------- gathered attention, bf16 qkv, balanced head->XCD schedule --------
// Phase A: 4 lanes per neighbor (lane = grp*4+sub? no: grp = lane>>2, sub = lane&3);
//   group loads the 128B K row as 2x64B sectors -> 1-2 transactions per neighbor.
//   kn computed inline (self-dot) -> no kn table, no scattered kn gather.
__global__ __launch_bounds__(256) void attn_k(
    const unsigned short* __restrict__ qkv,   // [n][1536] bf16
    const int* __restrict__ indices, const float* __restrict__ dsel,
    const float* __restrict__ lam, unsigned short* __restrict__ xo, int layer)
{
    int xcd = blockIdx.x & 7;
    int t = blockIdx.x >> 3;
    int hh, blk;
    int c0 = g_s0cnt[xcd];
    if (t < c0) {
        hh = g_s0h[xcd]; blk = g_s0base[xcd] + t;
    } else {
        t -= c0;
        int c1 = g_s1cnt[xcd];
        if (t < c1) {
            hh = g_s1h[xcd]; blk = t;
        } else if (xcd == 7 && t - c1 < 1024) {
            hh = 0; blk = t - c1;
        } else {
            return;
        }
    }

    int wid = threadIdx.x >> 6, lane = threadIdx.x & 63;
    int n = blk * 4 + wid;
    int Kh = 32 + 16 * hh + (hh == 7 ? 16 : 0);   // 32..160, multiples of 16

    __shared__ __align__(16) float qs[4][64];
    __shared__ float asc[4][KMAX];
    __shared__ int   sidx[4][KMAX];

    float qd = b2f(qkv[(size_t)n * 1536 + hh * 64 + lane]);
    qs[wid][lane] = qd;
    float qn2 = wsum(qd * qd);
    float sp = log1pf(expf(lam[layer * NHEAD + hh]));

    const int* irow = indices + (size_t)n * KMAX;
    const float* drow = dsel + (size_t)n * KMAX;

    // ---- Phase A: 16 neighbors per wave-iteration, 4 lanes each ----
    int sub = lane & 3, grp = lane >> 2;
    // lane's q dims: [sub*8 .. sub*8+7] and [32+sub*8 .. 32+sub*8+7]
    float qv[16];
#pragma unroll
    for (int c = 0; c < 2; c++) {
        float4 ta = *(const float4*)&qs[wid][c * 32 + sub * 8];
        float4 tb = *(const float4*)&qs[wid][c * 32 + sub * 8 + 4];
        qv[c * 8 + 0] = ta.x; qv[c * 8 + 1] = ta.y; qv[c * 8 + 2] = ta.z; qv[c * 8 + 3] = ta.w;
        qv[c * 8 + 4] = tb.x; qv[c * 8 + 5] = tb.y; qv[c * 8 + 6] = tb.z; qv[c * 8 + 7] = tb.w;
    }

    int iters = Kh >> 4;
    for (int it = 0; it < iters; it++) {
        int kk = it * 16 + grp;
        int idx = irow[kk];
        const uint4* krow = (const uint4*)(qkv + (size_t)idx * 1536 + 512 + hh * 64);
        uint4 ka = krow[sub];        // dims sub*8 .. sub*8+7   (64B sector across 4 lanes)
        uint4 kb = krow[4 + sub];    // dims 32+sub*8 ..        (second sector)
        unsigned kw[8];
        *(uint4*)&kw[0] = ka;
        *(uint4*)&kw[4] = kb;
        float dp = 0.f, knp = 0.f;
#pragma unroll
        for (int w = 0; w < 8; w++) {
            float lo = __uint_as_float(kw[w] << 16);
            float hi = __uint_as_float(kw[w] & 0xFFFF0000u);
            dp += qv[2 * w] * lo + qv[2 * w + 1] * hi;
            knp += lo * lo + hi * hi;
        }
        dp += __shfl_xor(dp, 1, 64);
        dp += __shfl_xor(dp, 2, 64);
        knp += __shfl_xor(knp, 1, 64);
        knp += __shfl_xor(knp, 2, 64);
        float dd = drow[kk];
        float dec = expf(-sp * dd) + 1e-6f;
        float s = (dp - 0.5f * (qn2 + knp)) * 0.125f + logf(dec);
        if (sub == 0) {
            asc[wid][kk] = s;
            sidx[wid][kk] = idx;
        }
    }

    // ---- Phase B: softmax (read raw scores from LDS, write normalized) ----
    float s0 = (lane < Kh) ? asc[wid][lane] : -1e30f;
    float s1 = (lane + 64 < Kh) ? asc[wid][lane + 64] : -1e30f;
    float s2 = (lane + 128 < Kh) ? asc[wid][lane + 128] : -1e30f;
    float mx = wmax(fmaxf(fmaxf(s0, s1), s2));
    float e0 = (s0 > -1e29f) ? expf(s0 - mx) : 0.f;
    float e1 = (s1 > -1e29f) ? expf(s1 - mx) : 0.f;
    float e2 = (s2 > -1e29f) ? expf(s2 - mx) : 0.f;
    float se = wsum(e0 + e1 + e2);
    float inv = 1.f / se;
    if (lane < Kh)       asc[wid][lane]       = e0 * inv;
    if (lane + 64 < Kh)  asc[wid][lane + 64]  = e1 * inv;
    if (lane + 128 < Kh) asc[wid][lane + 128] = e2 * inv;

    // ---- Phase C: PV, 8 lanes per neighbor (lane = g*8+q), uint4 V loads ----
    int g = lane >> 3, q = lane & 7;
    const uint4* vb = (const uint4*)(qkv + 1024 + hh * 64 + q * 8);  // +idx*192 per row
    float a8[8] = {};
    int k0 = 0;
    int kmain = Kh & ~31;
    for (; k0 < kmain; k0 += 32) {
        int ii[4]; float aa[4]; uint4 vv[4];
#pragma unroll
        for (int u = 0; u < 4; u++) {
            int kk = k0 + u * 8 + g;
            ii[u] = sidx[wid][kk];
            aa[u] = asc[wid][kk];
        }
#pragma unroll
        for (int u = 0; u < 4; u++) vv[u] = vb[(size_t)ii[u] * 192];
#pragma unroll
        for (int u = 0; u < 4; u++) {
            const unsigned short* vp = (const unsigned short*)&vv[u];
#pragma unroll
            for (int d = 0; d < 8; d++) a8[d] += aa[u] * b2f(vp[d]);
        }
    }
    if (Kh & 16) {
        int ii[2]; float aa[2]; uint4 vv[2];
#pragma unroll
        for (int u = 0; u < 2; u++) {
            int kk = k0 + u * 8 + g;
            ii[u] = sidx[wid][kk];
            aa[u] = asc[wid][kk];
        }
#pragma unroll
        for (int u = 0; u < 2; u++) vv[u] = vb[(size_t)ii[u] * 192];
#pragma unroll
        for (int u = 0; u < 2; u++) {
            const unsigned short* vp = (const unsigned short*)&vv[u];
#pragma unroll
            for (int d = 0; d < 8; d++) a8[d] += aa[u] * b2f(vp[d]);
        }
    }
#pragma unroll
    for (int d = 0; d < 8; d++) {
        a8[d] += __shfl_xor(a8[d], 8, 64);
        a8[d] += __shfl_xor(a8[d], 16, 64);
        a8[d] += __shfl_xor(a8[d], 32, 64);
    }
    if (lane < 8) {
        unsigned o[4];
#pragma unroll
        for (int p = 0; p < 4; p++)
            o[p] = ((unsigned)f2b(a8[2 * p + 1]) << 16) | (unsigned)f2b(a8[2 * p]);
        *(uint4*)(xo + (size_t)n * DMODEL + hh * 64 + lane * 8) = *(uint4*)o;
    }
}

// ---------------- column partial sums ----------------
__global__ __launch_bounds__(512) void colpart_k(const float* __restrict__ Y, float* __restrict__ part)
{
    int c = threadIdx.x;
    int blk = blockIdx.x;
    const float* p = Y + (size_t)blk * 16 * DMODEL + c;
    float s = 0.f;
#pragma unroll
    for (int r = 0; r < 16; r++) s += p[r * DMODEL];
    part[blk * DMODEL + c] = s;
}

// ---------------- finish mean + head GEMV ----------------
__global__ __launch_bounds__(512) void finhead_k(
    const float* __restrict__ part, const float* __restrict__ head_w,
    const float* __restrict__ head_b, float* __restrict__ out)
{
    __shared__ float mv[DMODEL];
    int c = threadIdx.x;
    float s = 0.f;
    for (int i = 0; i < 256; i++) s += part[i * DMODEL + c];
    mv[c] = s * (1.f / NTOK);
    __syncthreads();
    if (c < 64) {
        float a0 = 0.f, a1 = 0.f;
        for (int d = c; d < DMODEL; d += 64) {
            float m = mv[d];
            a0 += m * head_w[d * NCLS + 0];
            a1 += m * head_w[d * NCLS + 1];
        }
        a0 = wsum(a0);
        a1 = wsum(a1);
        if (c == 0) { out[0] = a0 + head_b[0]; out[1] = a1 + head_b[1]; }
    }
}

extern "C" void kernel_launch(void* const* d_in, const int* in_sizes, int n_in,
                              void* d_out, int out_size, void* d_ws, size_t ws_size,
                              hipStream_t stream)
{
    const float* x        = (const float*)d_in[0];
    const float* distance = (const float*)d_in[1];
    const int*   indices  = (const int*)d_in[2];
    const float* adapter_w = (const float*)d_in[5];
    const float* adapter_b = (const float*)d_in[6];
    const float* res_w     = (const float*)d_in[7];
    const float* res_b     = (const float*)d_in[8];
    const float* ln1_g     = (const float*)d_in[9];
    const float* ln1_b     = (const float*)d_in[10];
    const float* qkv_w     = (const float*)d_in[11];
    const float* qkv_b     = (const float*)d_in[12];
    const float* proj_w    = (const float*)d_in[13];
    const float* proj_b    = (const float*)d_in[14];
    const float* ln2_g     = (const float*)d_in[15];
    const float* ln2_b     = (const float*)d_in[16];
    const float* fc1_w     = (const float*)d_in[17];
    const float* fc1_b     = (const float*)d_in[18];
    const float* fc2_w     = (const float*)d_in[19];
    const float* fc2_b     = (const float*)d_in[20];
    const float* lam       = (const float*)d_in[21];
    const float* lnf_g     = (const float*)d_in[22];
    const float* lnf_b     = (const float*)d_in[23];
    const float* head_w    = (const float*)d_in[24];
    const float* head_b    = (const float*)d_in[25];
    float* out = (float*)d_out;

    char* wsb = (char*)d_ws;
    float* h   = (float*)(wsb);                         // 8 MB
    float* h0  = (float*)(wsb + (8u << 20));            // 8 MB; dead during layers -> dsel
    float* dsel = (float*)(wsb + (8u << 20));           // 2.6 MB
    char* shared = wsb + (16u << 20);                   // 24 MB shared region
    unsigned short* xb    = (unsigned short*)shared;                // 8 MB (dead after adapter)
    unsigned short* qkvbb = (unsigned short*)shared;                // 12 MB bf16
    unsigned short* fc1b  = (unsigned short*)shared;                // 16 MB (after attn)
    unsigned short* adapter_wt = (unsigned short*)(shared + (8u << 20));  // 1 MB
    unsigned short* res_wt     = (unsigned short*)(shared + (9u << 20));  // 0.5 MB
    unsigned short* lnb  = (unsigned short*)(wsb + (40u << 20));    // 4 MB (also h0b)
    unsigned short* h0b  = lnb;
    unsigned short* xob  = (unsigned short*)(wsb + (44u << 20));    // 4 MB
    unsigned short* qkv_wt = (unsigned short*)(wsb + (48u << 20));  // 3 MB
    unsigned short* proj_wt = (unsigned short*)(wsb + (51u << 20)); // 1 MB
    unsigned short* fc1_wt  = (unsigned short*)(wsb + (52u << 20)); // 4 MB
    unsigned short* fc2_wt  = (unsigned short*)(wsb + (56u << 20)); // 4 MB
    float* part = (float*)(wsb + (60u << 20));                      // 512 KB

    dim3 blk(256);

    // --- conversions (batched over layers via z) ---
    xcvt_k<<<(NTOK * EMB) / 2048, blk, 0, stream>>>(x, xb);
    wcvt_k<<<dim3(EMB / 64, DMODEL / 64, 1), blk, 0, stream>>>(adapter_w, adapter_wt, EMB, DMODEL);
    wcvt_k<<<dim3(DMODEL / 64, DMODEL / 64, 1), blk, 0, stream>>>(res_w, res_wt, DMODEL, DMODEL);
    wcvt_k<<<dim3(DMODEL / 64, 1536 / 64, NLAYER), blk, 0, stream>>>(qkv_w, qkv_wt, DMODEL, 1536);
    wcvt_k<<<dim3(DMODEL / 64, DMODEL / 64, NLAYER), blk, 0, stream>>>(proj_w, proj_wt, DMODEL, DMODEL);
    wcvt_k<<<dim3(DMODEL / 64, 2048 / 64, NLAYER), blk, 0, stream>>>(fc1_w, fc1_wt, DMODEL, 2048);
    wcvt_k<<<dim3(2048 / 64, DMODEL / 64, NLAYER), blk, 0, stream>>>(fc2_w, fc2_wt, 2048, DMODEL);

    // --- adapter: h0 = x @ adapter_w + b ---
    mgemm_k<64, 64, 2, 2, 4><<<dim3(NTOK / 64, DMODEL / 64), blk, 0, stream>>>(
        xb, adapter_wt, adapter_b, nullptr, h0, h0b, NTOK, DMODEL, EMB);
    // --- h = h0 + relu(h0 @ res_w + b) ---
    mgemm_k<64, 64, 2, 2, 1><<<dim3(NTOK / 64, DMODEL / 64), blk, 0, stream>>>(
        h0b, res_wt, res_b, h0, h, nullptr, NTOK, DMODEL, DMODEL);

    // dsel: h0 now dead until lnf
    dsel_k<<<NTOK, blk, 0, stream>>>(distance, indices, dsel);

    for (int l = 0; l < NLAYER; l++) {
        ln_k<1><<<NTOK, blk, 0, stream>>>(h, ln1_g + l * DMODEL, ln1_b + l * DMODEL, lnb, 1e-5f);
        mgemm_k<64, 128, 2, 2, 5><<<dim3(NTOK / 64, 1536 / 128), blk, 0, stream>>>(
            lnb, qkv_wt + (size_t)l * 1536 * DMODEL, qkv_b + l * 1536, nullptr,
            nullptr, qkvbb, NTOK, 1536, DMODEL);
        attn_k<<<ATTN_BLOCKS, blk, 0, stream>>>(qkvbb, indices, dsel, lam, xob, l);
        mgemm_k<64, 64, 2, 2, 3><<<dim3(NTOK / 64, DMODEL / 64), blk, 0, stream>>>(
            xob, proj_wt + (size_t)l * DMODEL * DMODEL, proj_b + l * DMODEL, h,
            h, nullptr, NTOK, DMODEL, DMODEL);
        ln_k<1><<<NTOK, blk, 0, stream>>>(h, ln2_g + l * DMODEL, ln2_b + l * DMODEL, lnb, 1e-5f);
        mgemm_k<64, 128, 2, 2, 2><<<dim3(NTOK / 64, 2048 / 128), blk, 0, stream>>>(
            lnb, fc1_wt + (size_t)l * 2048 * DMODEL, fc1_b + l * 2048, nullptr,
            nullptr, fc1b, NTOK, 2048, DMODEL);
        mgemm_k<64, 64, 2, 2, 3><<<dim3(NTOK / 64, DMODEL / 64), blk, 0, stream>>>(
            fc1b, fc2_wt + (size_t)l * DMODEL * 2048, fc2_b + l * DMODEL, h,
            h, nullptr, NTOK, DMODEL, 2048);
    }

    ln_k<0><<<NTOK, blk, 0, stream>>>(h, lnf_g, lnf_b, h0, 1e-6f);
    colpart_k<<<256, 512, 0, stream>>>(h0, part);
    finhead_k<<<1, 512, 0, stream>>>(part, head_w, head_b, out);
}

// Round 10
// 368.652 us; speedup vs baseline: 1.3200x; 1.0452x over previous
//
#include <hip/hip_runtime.h>
#include <hip/hip_bf16.h>

#define NTOK 4096
#define EMB 1024
#define DMODEL 512
#define NHEAD 8
#define NLAYER 2
#define NCLS 2
#define KMAX 160

typedef __attribute__((ext_vector_type(8))) short bf16x8;
typedef __attribute__((ext_vector_type(4))) float f32x4;

__device__ inline unsigned short f2b(float f) {
    unsigned u = __float_as_uint(f);
    u = u + 0x7FFFu + ((u >> 16) & 1u);
    return (unsigned short)(u >> 16);
}
__device__ inline float b2f(unsigned short s) {
    return __uint_as_float((unsigned)s << 16);
}

__device__ inline float wsum(float v) {
    for (int o = 32; o > 0; o >>= 1) v += __shfl_xor(v, o, 64);
    return v;
}
__device__ inline float wmax(float v) {
    for (int o = 32; o > 0; o >>= 1) v = fmaxf(v, __shfl_xor(v, o, 64));
    return v;
}

// async global->LDS, 16 B per lane. dest must be wave-uniform base + lane*16.
typedef __attribute__((address_space(3))) unsigned lds_u32_t;
typedef __attribute__((address_space(1))) const unsigned glb_u32_t;
__device__ inline void gload16(const void* g, void* l) {
    __builtin_amdgcn_global_load_lds((glb_u32_t*)(unsigned long long)g,
                                     (lds_u32_t*)(unsigned)(unsigned long long)l,
                                     16, 0, 0);
}

// Balanced head->XCD schedule: work blocks of 4 rows, 1024 blocks/head.
__device__ const int g_s0cnt[8]  = {576, 448, 720, 144, 365, 490, 460, 159};
__device__ const int g_s0h[8]    = {7, 7, 6, 6, 5, 4, 3, 2};
__device__ const int g_s0base[8] = {0, 576, 160, 880, 659, 534, 564, 865};
__device__ const int g_s1cnt[8]  = {0, 160, 0, 659, 534, 564, 865, 1024};
__device__ const int g_s1h[8]    = {0, 6, 0, 5, 4, 3, 2, 1};
#define ATTN_BLOCKS (2207 * 8)

// ---------------- weight convert+transpose: W[K][N] f32 -> Wt[N][K] bf16 (z = layer) ---
__global__ __launch_bounds__(256) void wcvt_k(const float* __restrict__ W,
                                              unsigned short* __restrict__ Wt,
                                              int K, int N)
{
    __shared__ unsigned short tile[64][72];
    size_t ls = (size_t)K * N * blockIdx.z;
    const float* Wl = W + ls;
    unsigned short* Wtl = Wt + ls;
    int k0 = blockIdx.x * 64, n0 = blockIdx.y * 64;
    int t = threadIdx.x;
    int kl = t >> 2, nb = (t & 3) * 16;
    const float* src = Wl + (size_t)(k0 + kl) * N + n0 + nb;
#pragma unroll
    for (int i = 0; i < 4; i++) {
        float4 v = *(const float4*)(src + 4 * i);
        tile[nb + 4 * i + 0][kl] = f2b(v.x);
        tile[nb + 4 * i + 1][kl] = f2b(v.y);
        tile[nb + 4 * i + 2][kl] = f2b(v.z);
        tile[nb + 4 * i + 3][kl] = f2b(v.w);
    }
    __syncthreads();
    int nl = t >> 2, ks = (t & 3) * 16;
    unsigned short* dst = Wtl + (size_t)(n0 + nl) * K + k0 + ks;
    *(uint4*)dst = *(const uint4*)&tile[nl][ks];
    *(uint4*)(dst + 8) = *(const uint4*)&tile[nl][ks + 8];
}

// ---------------- x f32 -> bf16 flat ----------------
__global__ __launch_bounds__(256) void xcvt_k(const float* __restrict__ X,
                                              unsigned short* __restrict__ Xb)
{
    int i = (blockIdx.x * 256 + threadIdx.x) * 8;
    float4 a = *(const float4*)(X + i);
    float4 b = *(const float4*)(X + i + 4);
    unsigned short o[8];
    o[0] = f2b(a.x); o[1] = f2b(a.y); o[2] = f2b(a.z); o[3] = f2b(a.w);
    o[4] = f2b(b.x); o[5] = f2b(b.y); o[6] = f2b(b.z); o[7] = f2b(b.w);
    *(uint4*)(Xb + i) = *(const uint4*)o;
}

// ---------------- dsel[n][k] = distance[n][indices[n][k]] ----------------
__global__ __launch_bounds__(256) void dsel_k(const float* __restrict__ distance,
                                              const int* __restrict__ indices,
                                              float* __restrict__ dsel)
{
    int n = blockIdx.x, t = threadIdx.x;
    if (t < KMAX) {
        int idx = indices[(size_t)n * KMAX + t];
        dsel[(size_t)n * KMAX + t] = distance[(size_t)n * NTOK + idx];
    }
}

// ---------------- kn[n][h] = sum_d K[n,h,d]^2 from bf16 qkv ----------------
__global__ __launch_bounds__(512) void knb_k(const unsigned short* __restrict__ qkv,
                                             float* __restrict__ kn)
{
    int n = blockIdx.x;
    int hh = threadIdx.x >> 6, lane = threadIdx.x & 63;
    float kv = b2f(qkv[(size_t)n * 1536 + 512 + hh * 64 + lane]);
    float ks = wsum(kv * kv);
    if (lane == 0) kn[n * NHEAD + hh] = ks;
}

// ---------------- MFMA GEMM: double-buffered 2-phase, XOR-swizzled LDS ----------------
// LDS physical layout linear (gload_lds dest = base + tid*16B); global SOURCE column is
// inverse-swizzled so logical chunk c of row r lives at physical chunk c ^ ((r>>1)&3).
// Fragment ds_read applies the same XOR -> 2-way bank aliasing (free) instead of 8-way.
template <int BM, int BN, int WM, int WN, int MODE>
__global__ __launch_bounds__(256) void mgemm_k(
    const unsigned short* __restrict__ A, const unsigned short* __restrict__ Wt,
    const float* __restrict__ bias, const float* __restrict__ resid,
    float* __restrict__ Cf, unsigned short* __restrict__ Cb,
    int M, int N, int K)
{
    constexpr int SM = BM / WM;
    constexpr int SN = BN / WN;
    constexpr int MR = SM / 16;
    constexpr int NR = SN / 16;

    __shared__ unsigned short Asl[2][BM * 32];
    __shared__ unsigned short Bsl[2][BN * 32];

    int tid = threadIdx.x;
    int bm = blockIdx.x * BM, bn = blockIdx.y * BN;
    int lane = tid & 63, wid = tid >> 6;
    int wm = wid / WN, wn = wid % WN;
    int l15 = lane & 15, l4 = lane >> 4;

    f32x4 acc[MR][NR] = {};

    int sr = tid >> 2;                                   // staging row 0..63
    int scl = (((tid & 3) ^ ((sr >> 1) & 3))) * 8;       // swizzled SOURCE col (elems)
    int dst_off = sr * 32 + (tid & 3) * 8;               // linear dest (elems)
    const unsigned short* Asrc = A  + (size_t)(bm + sr) * K + scl;
    const unsigned short* Bsrc = Wt + (size_t)(bn + sr) * K + scl;

    // fragment read offsets (logical chunk l4 -> physical chunk l4 ^ ((row>>1)&3))
    int arow = wm * SM + l15;
    int brow = wn * SN + l15;
    int aoff0 = arow * 32 + (l4 ^ ((arow >> 1) & 3)) * 8;
    int boff0 = brow * 32 + (l4 ^ ((brow >> 1) & 3)) * 8;

    auto stage = [&](int buf, int k0) {
#pragma unroll
        for (int i = 0; i < BM / 64; i++)
            gload16(Asrc + (size_t)(i * 64) * K + k0, &Asl[buf][i * 64 * 32 + dst_off]);
#pragma unroll
        for (int i = 0; i < BN / 64; i++)
            gload16(Bsrc + (size_t)(i * 64) * K + k0, &Bsl[buf][i * 64 * 32 + dst_off]);
    };

    int nt = K / 32;
    stage(0, 0);
    __syncthreads();
    int cur = 0;
    for (int t = 0; t < nt; t++) {
        if (t + 1 < nt) stage(cur ^ 1, (t + 1) * 32);
        bf16x8 af[MR], bfr[NR];
#pragma unroll
        for (int mr = 0; mr < MR; mr++) af[mr] = *(const bf16x8*)&Asl[cur][aoff0 + mr * 16 * 32];
#pragma unroll
        for (int nr = 0; nr < NR; nr++) bfr[nr] = *(const bf16x8*)&Bsl[cur][boff0 + nr * 16 * 32];
#pragma unroll
        for (int mr = 0; mr < MR; mr++)
#pragma unroll
            for (int nr = 0; nr < NR; nr++)
                acc[mr][nr] = __builtin_amdgcn_mfma_f32_16x16x32_bf16(af[mr], bfr[nr], acc[mr][nr], 0, 0, 0);
        __syncthreads();
        cur ^= 1;
    }

#pragma unroll
    for (int mr = 0; mr < MR; mr++) {
#pragma unroll
        for (int nr = 0; nr < NR; nr++) {
            int col = bn + wn * SN + nr * 16 + l15;
            float bcol = bias[col];
#pragma unroll
            for (int r = 0; r < 4; r++) {
                int row = bm + wm * SM + mr * 16 + l4 * 4 + r;
                size_t off = (size_t)row * N + col;
                float v = acc[mr][nr][r] + bcol;
                if (MODE == 0) {
                    Cf[off] = v;
                } else if (MODE == 1) {
                    Cf[off] = resid[off] + fmaxf(v, 0.f);
                } else if (MODE == 2) {
                    float t3 = tanhf(0.7978845608028654f * (v + 0.044715f * v * v * v));
                    Cb[off] = f2b(0.5f * v * (1.f + t3));
                } else if (MODE == 3) {
                    Cf[off] = resid[off] + v;
                } else if (MODE == 4) {
                    Cf[off] = v;
                    Cb[off] = f2b(v);
                } else {
                    Cb[off] = f2b(v);
                }
            }
        }
    }
}

// ---------------- LayerNorm over D=512, one row per block ----------------
template <int OUTB>
__global__ __launch_bounds__(256) void ln_k(
    const float* __restrict__ X, const float* __restrict__ g,
    const float* __restrict__ bta, void* __restrict__ Yv, float eps)
{
    int row = blockIdx.x;
    int tid = threadIdx.x;
    const float* xr = X + (size_t)row * DMODEL;
    float v0 = xr[tid], v1 = xr[tid + 256];
    __shared__ float red[8];
    float s = wsum(v0 + v1);
    int wid = tid >> 6, lane = tid & 63;
    if (lane == 0) red[wid] = s;
    __syncthreads();
    float m = (red[0] + red[1] + red[2] + red[3]) * (1.f / DMODEL);
    float d0 = v0 - m, d1 = v1 - m;
    float sq = wsum(d0 * d0 + d1 * d1);
    if (lane == 0) red[4 + wid] = sq;
    __syncthreads();
    float var = (red[4] + red[5] + red[6] + red[7]) * (1.f / DMODEL);
    float rs = 1.0f / sqrtf(var + eps);
    float y0 = d0 * rs * g[tid] + bta[tid];
    float y1 = d1 * rs * g[tid + 256] + bta[tid + 256];
    if (OUTB) {
        unsigned short* Y = (unsigned short*)Yv;
        Y[(size_t)row * DMODEL + tid] = f2b(y0);
        Y[(size_t)row * DMODEL + tid + 256] = f2b(y1);
    } else {
        float* Y = (float*)Yv;
        Y[(size_t)row * DMODEL + tid] = y0;
        Y[(size_t)row * DMODEL + tid + 256] = y1;
    }
}

// ---------------- gathered attention, bf16 qkv, balanced head->XCD schedule --------
// Phase A: 4 lanes per neighbor, coalesced 2x64B K-row sectors, raw dot only.
// Phase B: lane-per-neighbor score finalization (kn table gather + exp/log once) + softmax.
// Phase C: 8 lanes per neighbor, uint4 V loads.
__global__ __launch_bounds__(256) void attn_k(
    const unsigned short* __restrict__ qkv,   // [n][1536] bf16
    const float* __restrict__ kn,             // [n][8]
    const int* __restrict__ indices, const float* __restrict__ dsel,
    const float* __restrict__ lam, unsigned short* __restrict__ xo, int layer)
{
    int xcd = blockIdx.x & 7;
    int t = blockIdx.x >> 3;
    int hh, blk;
    int c0 = g_s0cnt[xcd];
    if (t < c0) {
        hh = g_s0h[xcd]; blk = g_s0base[xcd] + t;
    } else {
        t -= c0;
        int c1 = g_s1cnt[xcd];
        if (t < c1) {
            hh = g_s1h[xcd]; blk = t;
        } else if (xcd == 7 && t - c1 < 1024) {
            hh = 0; blk = t - c1;
        } else {
            return;
        }
    }

    int wid = threadIdx.x >> 6, lane = threadIdx.x & 63;
    int n = blk * 4 + wid;
    int Kh = 32 + 16 * hh + (hh == 7 ? 16 : 0);   // 32..160, multiples of 16

    __shared__ __align__(16) float qs[4][64];
    __shared__ float asc[4][KMAX];
    __shared__ int   sidx[4][KMAX];

    float qd = b2f(qkv[(size_t)n * 1536 + hh * 64 + lane]);
    qs[wid][lane] = qd;
    float qn2 = wsum(qd * qd);
    float sp = log1pf(expf(lam[layer * NHEAD + hh]));

    const int* irow = indices + (size_t)n * KMAX;
    const float* drow = dsel + (size_t)n * KMAX;

    // ---- Phase A: 16 neighbors per iteration, 4 lanes each; raw dot only ----
    int sub = lane & 3, grp = lane >> 2;
    float qv[16];
#pragma unroll
    for (int c = 0; c < 2; c++) {
        float4 ta = *(const float4*)&qs[wid][c * 32 + sub * 8];
        float4 tb = *(const float4*)&qs[wid][c * 32 + sub * 8 + 4];
        qv[c * 8 + 0] = ta.x; qv[c * 8 + 1] = ta.y; qv[c * 8 + 2] = ta.z; qv[c * 8 + 3] = ta.w;
        qv[c * 8 + 4] = tb.x; qv[c * 8 + 5] = tb.y; qv[c * 8 + 6] = tb.z; qv[c * 8 + 7] = tb.w;
    }

    int iters = Kh >> 4;
    for (int it = 0; it < iters; it++) {
        int kk = it * 16 + grp;
        int idx = irow[kk];
        const uint4* krow = (const uint4*)(qkv + (size_t)idx * 1536 + 512 + hh * 64);
        uint4 ka = krow[sub];
        uint4 kb = krow[4 + sub];
        unsigned kw[8];
        *(uint4*)&kw[0] = ka;
        *(uint4*)&kw[4] = kb;
        float dp = 0.f;
#pragma unroll
        for (int w = 0; w < 8; w++) {
            float lo = __uint_as_float(kw[w] << 16);
            float hi = __uint_as_float(kw[w] & 0xFFFF0000u);
            dp += qv[2 * w] * lo + qv[2 * w + 1] * hi;
        }
        dp += __shfl_xor(dp, 1, 64);
        dp += __shfl_xor(dp, 2, 64);
        if (sub == 0) {
            asc[wid][kk] = dp;
            sidx[wid][kk] = idx;
        }
    }

    // ---- Phase B: finalize scores (kn gather + decay, once per neighbor) + softmax ----
    float s0 = -1e30f, s1 = -1e30f, s2 = -1e30f;
    {
        int kk = lane;
        if (kk < Kh) {
            float dp = asc[wid][kk];
            float knv = kn[sidx[wid][kk] * NHEAD + hh];
            float dec = expf(-sp * drow[kk]) + 1e-6f;
            s0 = (dp - 0.5f * (qn2 + knv)) * 0.125f + logf(dec);
        }
        kk = lane + 64;
        if (kk < Kh) {
            float dp = asc[wid][kk];
            float knv = kn[sidx[wid][kk] * NHEAD + hh];
            float dec = expf(-sp * drow[kk]) + 1e-6f;
            s1 = (dp - 0.5f * (qn2 + knv)) * 0.125f + logf(dec);
        }
        kk = lane + 128;
        if (kk < Kh) {
            float dp = asc[wid][kk];
            float knv = kn[sidx[wid][kk] * NHEAD + hh];
            float dec = expf(-sp * drow[kk]) + 1e-6f;
            s2 = (dp - 0.5f * (qn2 + knv)) * 0.125f + logf(dec);
        }
    }
    float mx = wmax(fmaxf(fmaxf(s0, s1), s2));
    float e0 = (s0 > -1e29f) ? expf(s0 - mx) : 0.f;
    float e1 = (s1 > -1e29f) ? expf(s1 - mx) : 0.f;
    float e2 = (s2 > -1e29f) ? expf(s2 - mx) : 0.f;
    float se = wsum(e0 + e1 + e2);
    float inv = 1.f / se;
    if (lane < Kh)       asc[wid][lane]       = e0 * inv;
    if (lane + 64 < Kh)  asc[wid][lane + 64]  = e1 * inv;
    if (lane + 128 < Kh) asc[wid][lane + 128] = e2 * inv;

    // ---- Phase C: PV, 8 lanes per neighbor (lane = g*8+q), uint4 V loads ----
    int g = lane >> 3, q = lane & 7;
    const uint4* vb = (const uint4*)(qkv + 1024 + hh * 64 + q * 8);  // +idx*192 per row
    float a8[8] = {};
    int k0 = 0;
    int kmain = Kh & ~31;
    for (; k0 < kmain; k0 += 32) {
        int ii[4]; float aa[4]; uint4 vv[4];
#pragma unroll
        for (int u = 0; u < 4; u++) {
            int kk = k0 + u * 8 + g;
            ii[u] = sidx[wid][kk];
            aa[u] = asc[wid][kk];
        }
#pragma unroll
        for (int u = 0; u < 4; u++) vv[u] = vb[(size_t)ii[u] * 192];
#pragma unroll
        for (int u = 0; u < 4; u++) {
            const unsigned short* vp = (const unsigned short*)&vv[u];
#pragma unroll
            for (int d = 0; d < 8; d++) a8[d] += aa[u] * b2f(vp[d]);
        }
    }
    if (Kh & 16) {
        int ii[2]; float aa[2]; uint4 vv[2];
#pragma unroll
        for (int u = 0; u < 2; u++) {
            int kk = k0 + u * 8 + g;
            ii[u] = sidx[wid][kk];
            aa[u] = asc[wid][kk];
        }
#pragma unroll
        for (int u = 0; u < 2; u++) vv[u] = vb[(size_t)ii[u] * 192];
#pragma unroll
        for (int u = 0; u < 2; u++) {
            const unsigned short* vp = (const unsigned short*)&vv[u];
#pragma unroll
            for (int d = 0; d < 8; d++) a8[d] += aa[u] * b2f(vp[d]);
        }
    }
#pragma unroll
    for (int d = 0; d < 8; d++) {
        a8[d] += __shfl_xor(a8[d], 8, 64);
        a8[d] += __shfl_xor(a8[d], 16, 64);
        a8[d] += __shfl_xor(a8[d], 32, 64);
    }
    if (lane < 8) {
        unsigned o[4];
#pragma unroll
        for (int p = 0; p < 4; p++)
            o[p] = ((unsigned)f2b(a8[2 * p + 1]) << 16) | (unsigned)f2b(a8[2 * p]);
        *(uint4*)(xo + (size_t)n * DMODEL + hh * 64 + lane * 8) = *(uint4*)o;
    }
}

// ---------------- column partial sums ----------------
__global__ __launch_bounds__(512) void colpart_k(const float* __restrict__ Y, float* __restrict__ part)
{
    int c = threadIdx.x;
    int blk = blockIdx.x;
    const float* p = Y + (size_t)blk * 16 * DMODEL + c;
    float s = 0.f;
#pragma unroll
    for (int r = 0; r < 16; r++) s += p[r * DMODEL];
    part[blk * DMODEL + c] = s;
}

// ---------------- finish mean + head GEMV ----------------
__global__ __launch_bounds__(512) void finhead_k(
    const float* __restrict__ part, const float* __restrict__ head_w,
    const float* __restrict__ head_b, float* __restrict__ out)
{
    __shared__ float mv[DMODEL];
    int c = threadIdx.x;
    float s = 0.f;
    for (int i = 0; i < 256; i++) s += part[i * DMODEL + c];
    mv[c] = s * (1.f / NTOK);
    __syncthreads();
    if (c < 64) {
        float a0 = 0.f, a1 = 0.f;
        for (int d = c; d < DMODEL; d += 64) {
            float m = mv[d];
            a0 += m * head_w[d * NCLS + 0];
            a1 += m * head_w[d * NCLS + 1];
        }
        a0 = wsum(a0);
        a1 = wsum(a1);
        if (c == 0) { out[0] = a0 + head_b[0]; out[1] = a1 + head_b[1]; }
    }
}

extern "C" void kernel_launch(void* const* d_in, const int* in_sizes, int n_in,
                              void* d_out, int out_size, void* d_ws, size_t ws_size,
                              hipStream_t stream)
{
    const float* x        = (const float*)d_in[0];
    const float* distance = (const float*)d_in[1];
    const int*   indices  = (const int*)d_in[2];
    const float* adapter_w = (const float*)d_in[5];
    const float* adapter_b = (const float*)d_in[6];
    const float* res_w     = (const float*)d_in[7];
    const float* res_b     = (const float*)d_in[8];
    const float* ln1_g     = (const float*)d_in[9];
    const float* ln1_b     = (const float*)d_in[10];
    const float* qkv_w     = (const float*)d_in[11];
    const float* qkv_b     = (const float*)d_in[12];
    const float* proj_w    = (const float*)d_in[13];
    const float* proj_b    = (const float*)d_in[14];
    const float* ln2_g     = (const float*)d_in[15];
    const float* ln2_b     = (const float*)d_in[16];
    const float* fc1_w     = (const float*)d_in[17];
    const float* fc1_b     = (const float*)d_in[18];
    const float* fc2_w     = (const float*)d_in[19];
    const float* fc2_b     = (const float*)d_in[20];
    const float* lam       = (const float*)d_in[21];
    const float* lnf_g     = (const float*)d_in[22];
    const float* lnf_b     = (const float*)d_in[23];
    const float* head_w    = (const float*)d_in[24];
    const float* head_b    = (const float*)d_in[25];
    float* out = (float*)d_out;

    char* wsb = (char*)d_ws;
    float* h   = (float*)(wsb);                         // 8 MB
    float* h0  = (float*)(wsb + (8u << 20));            // 8 MB; dead during layers -> dsel
    float* dsel = (float*)(wsb + (8u << 20));           // 2.6 MB
    char* shared = wsb + (16u << 20);                   // 24 MB shared region
    unsigned short* xb    = (unsigned short*)shared;                // 8 MB (dead after adapter)
    unsigned short* qkvbb = (unsigned short*)shared;                // 12 MB bf16
    unsigned short* fc1b  = (unsigned short*)shared;                // 16 MB (after attn)
    unsigned short* adapter_wt = (unsigned short*)(shared + (8u << 20));  // 1 MB
    unsigned short* res_wt     = (unsigned short*)(shared + (9u << 20));  // 0.5 MB
    unsigned short* lnb  = (unsigned short*)(wsb + (40u << 20));    // 4 MB (also h0b)
    unsigned short* h0b  = lnb;
    unsigned short* xob  = (unsigned short*)(wsb + (44u << 20));    // 4 MB
    unsigned short* qkv_wt = (unsigned short*)(wsb + (48u << 20));  // 3 MB
    unsigned short* proj_wt = (unsigned short*)(wsb + (51u << 20)); // 1 MB
    unsigned short* fc1_wt  = (unsigned short*)(wsb + (52u << 20)); // 4 MB
    unsigned short* fc2_wt  = (unsigned short*)(wsb + (56u << 20)); // 4 MB
    float* kn   = (float*)(wsb + (60u << 20));                      // 128 KB
    float* part = (float*)(wsb + (60u << 20) + (1u << 18));         // 512 KB

    dim3 blk(256);

    // --- conversions (batched over layers via z) ---
    xcvt_k<<<(NTOK * EMB) / 2048, blk, 0, stream>>>(x, xb);
    wcvt_k<<<dim3(EMB / 64, DMODEL / 64, 1), blk, 0, stream>>>(adapter_w, adapter_wt, EMB, DMODEL);
    wcvt_k<<<dim3(DMODEL / 64, DMODEL / 64, 1), blk, 0, stream>>>(res_w, res_wt, DMODEL, DMODEL);
    wcvt_k<<<dim3(DMODEL / 64, 1536 / 64, NLAYER), blk, 0, stream>>>(qkv_w, qkv_wt, DMODEL, 1536);
    wcvt_k<<<dim3(DMODEL / 64, DMODEL / 64, NLAYER), blk, 0, stream>>>(proj_w, proj_wt, DMODEL, DMODEL);
    wcvt_k<<<dim3(DMODEL / 64, 2048 / 64, NLAYER), blk, 0, stream>>>(fc1_w, fc1_wt, DMODEL, 2048);
    wcvt_k<<<dim3(2048 / 64, DMODEL / 64, NLAYER), blk, 0, stream>>>(fc2_w, fc2_wt, 2048, DMODEL);

    // --- adapter: h0 = x @ adapter_w + b ---
    mgemm_k<64, 64, 2, 2, 4><<<dim3(NTOK / 64, DMODEL / 64), blk, 0, stream>>>(
        xb, adapter_wt, adapter_b, nullptr, h0, h0b, NTOK, DMODEL, EMB);
    // --- h = h0 + relu(h0 @ res_w + b) ---
    mgemm_k<64, 64, 2, 2, 1><<<dim3(NTOK / 64, DMODEL / 64), blk, 0, stream>>>(
        h0b, res_wt, res_b, h0, h, nullptr, NTOK, DMODEL, DMODEL);

    // dsel: h0 now dead until lnf
    dsel_k<<<NTOK, blk, 0, stream>>>(distance, indices, dsel);

    for (int l = 0; l < NLAYER; l++) {
        ln_k<1><<<NTOK, blk, 0, stream>>>(h, ln1_g + l * DMODEL, ln1_b + l * DMODEL, lnb, 1e-5f);
        mgemm_k<64, 128, 2, 2, 5><<<dim3(NTOK / 64, 1536 / 128), blk, 0, stream>>>(
            lnb, qkv_wt + (size_t)l * 1536 * DMODEL, qkv_b + l * 1536, nullptr,
            nullptr, qkvbb, NTOK, 1536, DMODEL);
        knb_k<<<NTOK, 512, 0, stream>>>(qkvbb, kn);
        attn_k<<<ATTN_BLOCKS, blk, 0, stream>>>(qkvbb, kn, indices, dsel, lam, xob, l);
        mgemm_k<64, 64, 2, 2, 3><<<dim3(NTOK / 64, DMODEL / 64), blk, 0, stream>>>(
            xob, proj_wt + (size_t)l * DMODEL * DMODEL, proj_b + l * DMODEL, h,
            h, nullptr, NTOK, DMODEL, DMODEL);
        ln_k<1><<<NTOK, blk, 0, stream>>>(h, ln2_g + l * DMODEL, ln2_b + l * DMODEL, lnb, 1e-5f);
        mgemm_k<64, 128, 2, 2, 2><<<dim3(NTOK / 64, 2048 / 128), blk, 0, stream>>>(
            lnb, fc1_wt + (size_t)l * 2048 * DMODEL, fc1_b + l * 2048, nullptr,
            nullptr, fc1b, NTOK, 2048, DMODEL);
        mgemm_k<64, 64, 2, 2, 3><<<dim3(NTOK / 64, DMODEL / 64), blk, 0, stream>>>(
            fc1b, fc2_wt + (size_t)l * DMODEL * 2048, fc2_b + l * DMODEL, h,
            h, nullptr, NTOK, DMODEL, 2048);
    }

    ln_k<0><<<NTOK, blk, 0, stream>>>(h, lnf_g, lnf_b, h0, 1e-6f);
    colpart_k<<<256, 512, 0, stream>>>(h0, part);
    finhead_k<<<1, 512, 0, stream>>>(part, head_w, head_b, out);
}

// Round 11
// 354.080 us; speedup vs baseline: 1.3743x; 1.0412x over previous
//
#include <hip/hip_runtime.h>
#include <hip/hip_bf16.h>

#define NTOK 4096
#define EMB 1024
#define DMODEL 512
#define NHEAD 8
#define NLAYER 2
#define NCLS 2
#define KMAX 160

typedef __attribute__((ext_vector_type(8))) short bf16x8;
typedef __attribute__((ext_vector_type(4))) float f32x4;

__device__ inline unsigned short f2b(float f) {
    unsigned u = __float_as_uint(f);
    u = u + 0x7FFFu + ((u >> 16) & 1u);
    return (unsigned short)(u >> 16);
}
__device__ inline float b2f(unsigned short s) {
    return __uint_as_float((unsigned)s << 16);
}

// v_dot2_f32_bf16: d = a.lo*b.lo + a.hi*b.hi + c  (packed bf16 pairs)
__device__ inline float dot2bf(unsigned a, unsigned b, float c) {
    float d;
    asm("v_dot2_f32_bf16 %0, %1, %2, %3" : "=v"(d) : "v"(a), "v"(b), "v"(c));
    return d;
}

__device__ inline float wsum(float v) {
    for (int o = 32; o > 0; o >>= 1) v += __shfl_xor(v, o, 64);
    return v;
}
__device__ inline float wmax(float v) {
    for (int o = 32; o > 0; o >>= 1) v = fmaxf(v, __shfl_xor(v, o, 64));
    return v;
}

// async global->LDS, 16 B per lane. dest must be wave-uniform base + lane*16.
typedef __attribute__((address_space(3))) unsigned lds_u32_t;
typedef __attribute__((address_space(1))) const unsigned glb_u32_t;
__device__ inline void gload16(const void* g, void* l) {
    __builtin_amdgcn_global_load_lds((glb_u32_t*)(unsigned long long)g,
                                     (lds_u32_t*)(unsigned)(unsigned long long)l,
                                     16, 0, 0);
}

// Balanced head->XCD schedule: work blocks of 4 rows, 1024 blocks/head.
__device__ const int g_s0cnt[8]  = {576, 448, 720, 144, 365, 490, 460, 159};
__device__ const int g_s0h[8]    = {7, 7, 6, 6, 5, 4, 3, 2};
__device__ const int g_s0base[8] = {0, 576, 160, 880, 659, 534, 564, 865};
__device__ const int g_s1cnt[8]  = {0, 160, 0, 659, 534, 564, 865, 1024};
__device__ const int g_s1h[8]    = {0, 6, 0, 5, 4, 3, 2, 1};
#define ATTN_BLOCKS (2207 * 8)

// ---------------- merged weight convert+transpose: all 6 weight groups, 1 dispatch ----
struct WSeg { const float* src; unsigned short* dst; int K; int N; int tile0; };
struct WSegs { WSeg s[6]; };

__global__ __launch_bounds__(256) void wcvt_all_k(WSegs segs)
{
    __shared__ unsigned short tile[64][72];
    int t0 = blockIdx.x;
    int si = 0;
#pragma unroll
    for (int i = 1; i < 6; i++) if (t0 >= segs.s[i].tile0) si = i;
    const float* src0 = segs.s[si].src;
    unsigned short* dst0 = segs.s[si].dst;
    int K = segs.s[si].K, N = segs.s[si].N;
    int lt = t0 - segs.s[si].tile0;
    int tx = K >> 6, ty = N >> 6;
    int per = tx * ty;
    int l = lt / per, rr = lt - l * per;
    int k0 = (rr % tx) << 6, n0 = (rr / tx) << 6;
    size_t ls = (size_t)K * N * l;
    const float* Wl = src0 + ls;
    unsigned short* Wtl = dst0 + ls;

    int t = threadIdx.x;
    int kl = t >> 2, nb = (t & 3) * 16;
    const float* src = Wl + (size_t)(k0 + kl) * N + n0 + nb;
#pragma unroll
    for (int i = 0; i < 4; i++) {
        float4 v = *(const float4*)(src + 4 * i);
        tile[nb + 4 * i + 0][kl] = f2b(v.x);
        tile[nb + 4 * i + 1][kl] = f2b(v.y);
        tile[nb + 4 * i + 2][kl] = f2b(v.z);
        tile[nb + 4 * i + 3][kl] = f2b(v.w);
    }
    __syncthreads();
    int nl = t >> 2, ks = (t & 3) * 16;
    unsigned short* dst = Wtl + (size_t)(n0 + nl) * K + k0 + ks;
    *(uint4*)dst = *(const uint4*)&tile[nl][ks];
    *(uint4*)(dst + 8) = *(const uint4*)&tile[nl][ks + 8];
}

// ---------------- x f32 -> bf16 flat ----------------
__global__ __launch_bounds__(256) void xcvt_k(const float* __restrict__ X,
                                              unsigned short* __restrict__ Xb)
{
    int i = (blockIdx.x * 256 + threadIdx.x) * 8;
    float4 a = *(const float4*)(X + i);
    float4 b = *(const float4*)(X + i + 4);
    unsigned short o[8];
    o[0] = f2b(a.x); o[1] = f2b(a.y); o[2] = f2b(a.z); o[3] = f2b(a.w);
    o[4] = f2b(b.x); o[5] = f2b(b.y); o[6] = f2b(b.z); o[7] = f2b(b.w);
    *(uint4*)(Xb + i) = *(const uint4*)o;
}

// ---------------- dsel[n][k] = distance[n][indices[n][k]] ----------------
__global__ __launch_bounds__(256) void dsel_k(const float* __restrict__ distance,
                                              const int* __restrict__ indices,
                                              float* __restrict__ dsel)
{
    int n = blockIdx.x, t = threadIdx.x;
    if (t < KMAX) {
        int idx = indices[(size_t)n * KMAX + t];
        dsel[(size_t)n * KMAX + t] = distance[(size_t)n * NTOK + idx];
    }
}

// ---------------- MFMA GEMM: double-buffered, XOR-swizzled LDS ----------------
// MODE 5 (qkv) additionally writes kn[row][head] = sum over head cols of v^2
// (requires SN==64 so each wave owns exactly one head's columns).
template <int BM, int BN, int WM, int WN, int MODE>
__global__ __launch_bounds__(256) void mgemm_k(
    const unsigned short* __restrict__ A, const unsigned short* __restrict__ Wt,
    const float* __restrict__ bias, const float* __restrict__ resid,
    float* __restrict__ Cf, unsigned short* __restrict__ Cb,
    float* __restrict__ knout,
    int M, int N, int K)
{
    constexpr int SM = BM / WM;
    constexpr int SN = BN / WN;
    constexpr int MR = SM / 16;
    constexpr int NR = SN / 16;

    __shared__ unsigned short Asl[2][BM * 32];
    __shared__ unsigned short Bsl[2][BN * 32];

    int tid = threadIdx.x;
    int bm = blockIdx.x * BM, bn = blockIdx.y * BN;
    int lane = tid & 63, wid = tid >> 6;
    int wm = wid / WN, wn = wid % WN;
    int l15 = lane & 15, l4 = lane >> 4;

    f32x4 acc[MR][NR] = {};

    int sr = tid >> 2;
    int scl = (((tid & 3) ^ ((sr >> 1) & 3))) * 8;       // swizzled SOURCE col
    int dst_off = sr * 32 + (tid & 3) * 8;               // linear dest
    const unsigned short* Asrc = A  + (size_t)(bm + sr) * K + scl;
    const unsigned short* Bsrc = Wt + (size_t)(bn + sr) * K + scl;

    int arow = wm * SM + l15;
    int brow = wn * SN + l15;
    int aoff0 = arow * 32 + (l4 ^ ((arow >> 1) & 3)) * 8;
    int boff0 = brow * 32 + (l4 ^ ((brow >> 1) & 3)) * 8;

    auto stage = [&](int buf, int k0) {
#pragma unroll
        for (int i = 0; i < BM / 64; i++)
            gload16(Asrc + (size_t)(i * 64) * K + k0, &Asl[buf][i * 64 * 32 + dst_off]);
#pragma unroll
        for (int i = 0; i < BN / 64; i++)
            gload16(Bsrc + (size_t)(i * 64) * K + k0, &Bsl[buf][i * 64 * 32 + dst_off]);
    };

    int nt = K / 32;
    stage(0, 0);
    __syncthreads();
    int cur = 0;
    for (int t = 0; t < nt; t++) {
        if (t + 1 < nt) stage(cur ^ 1, (t + 1) * 32);
        bf16x8 af[MR], bfr[NR];
#pragma unroll
        for (int mr = 0; mr < MR; mr++) af[mr] = *(const bf16x8*)&Asl[cur][aoff0 + mr * 16 * 32];
#pragma unroll
        for (int nr = 0; nr < NR; nr++) bfr[nr] = *(const bf16x8*)&Bsl[cur][boff0 + nr * 16 * 32];
#pragma unroll
        for (int mr = 0; mr < MR; mr++)
#pragma unroll
            for (int nr = 0; nr < NR; nr++)
                acc[mr][nr] = __builtin_amdgcn_mfma_f32_16x16x32_bf16(af[mr], bfr[nr], acc[mr][nr], 0, 0, 0);
        __syncthreads();
        cur ^= 1;
    }

#pragma unroll
    for (int mr = 0; mr < MR; mr++) {
#pragma unroll
        for (int nr = 0; nr < NR; nr++) {
            int col = bn + wn * SN + nr * 16 + l15;
            float bcol = bias[col];
#pragma unroll
            for (int r = 0; r < 4; r++) {
                int row = bm + wm * SM + mr * 16 + l4 * 4 + r;
                size_t off = (size_t)row * N + col;
                float v = acc[mr][nr][r] + bcol;
                if (MODE == 0) {
                    Cf[off] = v;
                } else if (MODE == 1) {
                    Cf[off] = resid[off] + fmaxf(v, 0.f);
                } else if (MODE == 2) {
                    float t3 = tanhf(0.7978845608028654f * (v + 0.044715f * v * v * v));
                    Cb[off] = f2b(0.5f * v * (1.f + t3));
                } else if (MODE == 3) {
                    Cf[off] = resid[off] + v;
                } else if (MODE == 4) {
                    Cf[off] = v;
                    Cb[off] = f2b(v);
                } else {
                    Cb[off] = f2b(v);
                }
            }
        }
    }

    // fused kn for the K region of qkv output (cols 512..1024)
    if (MODE == 5) {
        int cbase = bn + wn * SN;
        if (cbase >= 512 && cbase < 1024) {
            int hh = (cbase - 512) >> 6;
#pragma unroll
            for (int mr = 0; mr < MR; mr++) {
#pragma unroll
                for (int r = 0; r < 4; r++) {
                    float p = 0.f;
#pragma unroll
                    for (int nr = 0; nr < NR; nr++) {
                        float v = acc[mr][nr][r] + bias[cbase + nr * 16 + l15];
                        p += v * v;
                    }
                    p += __shfl_xor(p, 1, 64);
                    p += __shfl_xor(p, 2, 64);
                    p += __shfl_xor(p, 4, 64);
                    p += __shfl_xor(p, 8, 64);
                    if (l15 == 0) {
                        int row = bm + wm * SM + mr * 16 + l4 * 4 + r;
                        knout[row * NHEAD + hh] = p;
                    }
                }
            }
        }
    }
}

// ---------------- LayerNorm over D=512, one row per block ----------------
template <int OUTB>
__global__ __launch_bounds__(256) void ln_k(
    const float* __restrict__ X, const float* __restrict__ g,
    const float* __restrict__ bta, void* __restrict__ Yv, float eps)
{
    int row = blockIdx.x;
    int tid = threadIdx.x;
    const float* xr = X + (size_t)row * DMODEL;
    float v0 = xr[tid], v1 = xr[tid + 256];
    __shared__ float red[8];
    float s = wsum(v0 + v1);
    int wid = tid >> 6, lane = tid & 63;
    if (lane == 0) red[wid] = s;
    __syncthreads();
    float m = (red[0] + red[1] + red[2] + red[3]) * (1.f / DMODEL);
    float d0 = v0 - m, d1 = v1 - m;
    float sq = wsum(d0 * d0 + d1 * d1);
    if (lane == 0) red[4 + wid] = sq;
    __syncthreads();
    float var = (red[4] + red[5] + red[6] + red[7]) * (1.f / DMODEL);
    float rs = 1.0f / sqrtf(var + eps);
    float y0 = d0 * rs * g[tid] + bta[tid];
    float y1 = d1 * rs * g[tid + 256] + bta[tid + 256];
    if (OUTB) {
        unsigned short* Y = (unsigned short*)Yv;
        Y[(size_t)row * DMODEL + tid] = f2b(y0);
        Y[(size_t)row * DMODEL + tid + 256] = f2b(y1);
    } else {
        float* Y = (float*)Yv;
        Y[(size_t)row * DMODEL + tid] = y0;
        Y[(size_t)row * DMODEL + tid + 256] = y1;
    }
}

// ---------------- gathered attention, bf16 qkv, balanced head->XCD schedule --------
// Phase A: 4 lanes per neighbor, coalesced K sectors, v_dot2_f32_bf16 with 4 accs.
// Phase B: lane-per-neighbor finalization (kn gather + exp/log once) + softmax.
// Phase C: 8 lanes per neighbor, uint4 V loads.
__global__ __launch_bounds__(256) void attn_k(
    const unsigned short* __restrict__ qkv,   // [n][1536] bf16
    const float* __restrict__ kn,             // [n][8]
    const int* __restrict__ indices, const float* __restrict__ dsel,
    const float* __restrict__ lam, unsigned short* __restrict__ xo, int layer)
{
    int xcd = blockIdx.x & 7;
    int t = blockIdx.x >> 3;
    int hh, blk;
    int c0 = g_s0cnt[xcd];
    if (t < c0) {
        hh = g_s0h[xcd]; blk = g_s0base[xcd] + t;
    } else {
        t -= c0;
        int c1 = g_s1cnt[xcd];
        if (t < c1) {
            hh = g_s1h[xcd]; blk = t;
        } else if (xcd == 7 && t - c1 < 1024) {
            hh = 0; blk = t - c1;
        } else {
            return;
        }
    }

    int wid = threadIdx.x >> 6, lane = threadIdx.x & 63;
    int n = blk * 4 + wid;
    int Kh = 32 + 16 * hh + (hh == 7 ? 16 : 0);   // 32..160, multiples of 16

    __shared__ __align__(16) unsigned qsp[4][32];   // q as packed bf16 pairs
    __shared__ float asc[4][KMAX];
    __shared__ int   sidx[4][KMAX];

    const unsigned short* qrow = qkv + (size_t)n * 1536 + hh * 64;
    float qd = b2f(qrow[lane]);
    if (lane < 32) qsp[wid][lane] = ((const unsigned*)qrow)[lane];
    float qn2 = wsum(qd * qd);
    float sp = log1pf(expf(lam[layer * NHEAD + hh]));

    const int* irow = indices + (size_t)n * KMAX;
    const float* drow = dsel + (size_t)n * KMAX;

    // ---- Phase A: 16 neighbors per iteration, 4 lanes each; dot2, 4 accumulators ----
    int sub = lane & 3, grp = lane >> 2;
    const uint4* qp = (const uint4*)&qsp[wid][0];
    uint4 qa = qp[sub], qb = qp[4 + sub];

    int iters = Kh >> 4;
    for (int it = 0; it < iters; it++) {
        int kk = it * 16 + grp;
        int idx = irow[kk];
        const uint4* krow = (const uint4*)(qkv + (size_t)idx * 1536 + 512 + hh * 64);
        uint4 ka = krow[sub];
        uint4 kb = krow[4 + sub];
        float d0 = 0.f, d1 = 0.f, d2 = 0.f, d3 = 0.f;
        d0 = dot2bf(ka.x, qa.x, d0); d1 = dot2bf(ka.y, qa.y, d1);
        d2 = dot2bf(ka.z, qa.z, d2); d3 = dot2bf(ka.w, qa.w, d3);
        d0 = dot2bf(kb.x, qb.x, d0); d1 = dot2bf(kb.y, qb.y, d1);
        d2 = dot2bf(kb.z, qb.z, d2); d3 = dot2bf(kb.w, qb.w, d3);
        float dp = (d0 + d1) + (d2 + d3);
        dp += __shfl_xor(dp, 1, 64);
        dp += __shfl_xor(dp, 2, 64);
        if (sub == 0) {
            asc[wid][kk] = dp;
            sidx[wid][kk] = idx;
        }
    }

    // ---- Phase B: finalize scores (kn gather + decay, once per neighbor) + softmax ----
    float s0 = -1e30f, s1 = -1e30f, s2 = -1e30f;
    {
        int kk = lane;
        if (kk < Kh) {
            float dp = asc[wid][kk];
            float knv = kn[sidx[wid][kk] * NHEAD + hh];
            float dec = expf(-sp * drow[kk]) + 1e-6f;
            s0 = (dp - 0.5f * (qn2 + knv)) * 0.125f + logf(dec);
        }
        kk = lane + 64;
        if (kk < Kh) {
            float dp = asc[wid][kk];
            float knv = kn[sidx[wid][kk] * NHEAD + hh];
            float dec = expf(-sp * drow[kk]) + 1e-6f;
            s1 = (dp - 0.5f * (qn2 + knv)) * 0.125f + logf(dec);
        }
        kk = lane + 128;
        if (kk < Kh) {
            float dp = asc[wid][kk];
            float knv = kn[sidx[wid][kk] * NHEAD + hh];
            float dec = expf(-sp * drow[kk]) + 1e-6f;
            s2 = (dp - 0.5f * (qn2 + knv)) * 0.125f + logf(dec);
        }
    }
    float mx = wmax(fmaxf(fmaxf(s0, s1), s2));
    float e0 = (s0 > -1e29f) ? expf(s0 - mx) : 0.f;
    float e1 = (s1 > -1e29f) ? expf(s1 - mx) : 0.f;
    float e2 = (s2 > -1e29f) ? expf(s2 - mx) : 0.f;
    float se = wsum(e0 + e1 + e2);
    float inv = 1.f / se;
    if (lane < Kh)       asc[wid][lane]       = e0 * inv;
    if (lane + 64 < Kh)  asc[wid][lane + 64]  = e1 * inv;
    if (lane + 128 < Kh) asc[wid][lane + 128] = e2 * inv;

    // ---- Phase C: PV, 8 lanes per neighbor (lane = g*8+q), uint4 V loads ----
    int g = lane >> 3, q = lane & 7;
    const uint4* vb = (const uint4*)(qkv + 1024 + hh * 64 + q * 8);  // +idx*192 per row
    float a8[8] = {};
    int k0 = 0;
    int kmain = Kh & ~31;
    for (; k0 < kmain; k0 += 32) {
        int ii[4]; float aa[4]; uint4 vv[4];
#pragma unroll
        for (int u = 0; u < 4; u++) {
            int kk = k0 + u * 8 + g;
            ii[u] = sidx[wid][kk];
            aa[u] = asc[wid][kk];
        }
#pragma unroll
        for (int u = 0; u < 4; u++) vv[u] = vb[(size_t)ii[u] * 192];
#pragma unroll
        for (int u = 0; u < 4; u++) {
            const unsigned short* vp = (const unsigned short*)&vv[u];
#pragma unroll
            for (int d = 0; d < 8; d++) a8[d] += aa[u] * b2f(vp[d]);
        }
    }
    if (Kh & 16) {
        int ii[2]; float aa[2]; uint4 vv[2];
#pragma unroll
        for (int u = 0; u < 2; u++) {
            int kk = k0 + u * 8 + g;
            ii[u] = sidx[wid][kk];
            aa[u] = asc[wid][kk];
        }
#pragma unroll
        for (int u = 0; u < 2; u++) vv[u] = vb[(size_t)ii[u] * 192];
#pragma unroll
        for (int u = 0; u < 2; u++) {
            const unsigned short* vp = (const unsigned short*)&vv[u];
#pragma unroll
            for (int d = 0; d < 8; d++) a8[d] += aa[u] * b2f(vp[d]);
        }
    }
#pragma unroll
    for (int d = 0; d < 8; d++) {
        a8[d] += __shfl_xor(a8[d], 8, 64);
        a8[d] += __shfl_xor(a8[d], 16, 64);
        a8[d] += __shfl_xor(a8[d], 32, 64);
    }
    if (lane < 8) {
        unsigned o[4];
#pragma unroll
        for (int p = 0; p < 4; p++)
            o[p] = ((unsigned)f2b(a8[2 * p + 1]) << 16) | (unsigned)f2b(a8[2 * p]);
        *(uint4*)(xo + (size_t)n * DMODEL + hh * 64 + lane * 8) = *(uint4*)o;
    }
}

// ---------------- column partial sums ----------------
__global__ __launch_bounds__(512) void colpart_k(const float* __restrict__ Y, float* __restrict__ part)
{
    int c = threadIdx.x;
    int blk = blockIdx.x;
    const float* p = Y + (size_t)blk * 16 * DMODEL + c;
    float s = 0.f;
#pragma unroll
    for (int r = 0; r < 16; r++) s += p[r * DMODEL];
    part[blk * DMODEL + c] = s;
}

// ---------------- finish mean + head GEMV ----------------
__global__ __launch_bounds__(512) void finhead_k(
    const float* __restrict__ part, const float* __restrict__ head_w,
    const float* __restrict__ head_b, float* __restrict__ out)
{
    __shared__ float mv[DMODEL];
    int c = threadIdx.x;
    float s = 0.f;
    for (int i = 0; i < 256; i++) s += part[i * DMODEL + c];
    mv[c] = s * (1.f / NTOK);
    __syncthreads();
    if (c < 64) {
        float a0 = 0.f, a1 = 0.f;
        for (int d = c; d < DMODEL; d += 64) {
            float m = mv[d];
            a0 += m * head_w[d * NCLS + 0];
            a1 += m * head_w[d * NCLS + 1];
        }
        a0 = wsum(a0);
        a1 = wsum(a1);
        if (c == 0) { out[0] = a0 + head_b[0]; out[1] = a1 + head_b[1]; }
    }
}

extern "C" void kernel_launch(void* const* d_in, const int* in_sizes, int n_in,
                              void* d_out, int out_size, void* d_ws, size_t ws_size,
                              hipStream_t stream)
{
    const float* x        = (const float*)d_in[0];
    const float* distance = (const float*)d_in[1];
    const int*   indices  = (const int*)d_in[2];
    const float* adapter_w = (const float*)d_in[5];
    const float* adapter_b = (const float*)d_in[6];
    const float* res_w     = (const float*)d_in[7];
    const float* res_b     = (const float*)d_in[8];
    const float* ln1_g     = (const float*)d_in[9];
    const float* ln1_b     = (const float*)d_in[10];
    const float* qkv_w     = (const float*)d_in[11];
    const float* qkv_b     = (const float*)d_in[12];
    const float* proj_w    = (const float*)d_in[13];
    const float* proj_b    = (const float*)d_in[14];
    const float* ln2_g     = (const float*)d_in[15];
    const float* ln2_b     = (const float*)d_in[16];
    const float* fc1_w     = (const float*)d_in[17];
    const float* fc1_b     = (const float*)d_in[18];
    const float* fc2_w     = (const float*)d_in[19];
    const float* fc2_b     = (const float*)d_in[20];
    const float* lam       = (const float*)d_in[21];
    const float* lnf_g     = (const float*)d_in[22];
    const float* lnf_b     = (const float*)d_in[23];
    const float* head_w    = (const float*)d_in[24];
    const float* head_b    = (const float*)d_in[25];
    float* out = (float*)d_out;

    char* wsb = (char*)d_ws;
    float* h   = (float*)(wsb);                         // 8 MB
    float* h0  = (float*)(wsb + (8u << 20));            // 8 MB; dead during layers -> dsel
    float* dsel = (float*)(wsb + (8u << 20));           // 2.6 MB
    char* shared = wsb + (16u << 20);                   // 24 MB shared region
    unsigned short* xb    = (unsigned short*)shared;                // 8 MB (dead after adapter)
    unsigned short* qkvbb = (unsigned short*)shared;                // 12 MB bf16
    unsigned short* fc1b  = (unsigned short*)shared;                // 16 MB (after attn)
    unsigned short* adapter_wt = (unsigned short*)(shared + (8u << 20));  // 1 MB
    unsigned short* res_wt     = (unsigned short*)(shared + (9u << 20));  // 0.5 MB
    unsigned short* lnb  = (unsigned short*)(wsb + (40u << 20));    // 4 MB (also h0b)
    unsigned short* h0b  = lnb;
    unsigned short* xob  = (unsigned short*)(wsb + (44u << 20));    // 4 MB
    unsigned short* qkv_wt = (unsigned short*)(wsb + (48u << 20));  // 3 MB
    unsigned short* proj_wt = (unsigned short*)(wsb + (51u << 20)); // 1 MB
    unsigned short* fc1_wt  = (unsigned short*)(wsb + (52u << 20)); // 4 MB
    unsigned short* fc2_wt  = (unsigned short*)(wsb + (56u << 20)); // 4 MB
    float* kn   = (float*)(wsb + (60u << 20));                      // 128 KB
    float* part = (float*)(wsb + (60u << 20) + (1u << 18));         // 512 KB

    dim3 blk(256);

    // --- conversions: x (bf16) + all weights in ONE dispatch ---
    xcvt_k<<<(NTOK * EMB) / 2048, blk, 0, stream>>>(x, xb);
    {
        WSegs segs;
        // tiles per seg: adapter 16*8=128, res 8*8=64, qkv 8*24*2=384,
        // proj 8*8*2=128, fc1 8*32*2=512, fc2 32*8*2=512  -> total 1728
        segs.s[0] = { adapter_w, adapter_wt, EMB,    DMODEL, 0 };
        segs.s[1] = { res_w,     res_wt,     DMODEL, DMODEL, 128 };
        segs.s[2] = { qkv_w,     qkv_wt,     DMODEL, 1536,   192 };
        segs.s[3] = { proj_w,    proj_wt,    DMODEL, DMODEL, 576 };
        segs.s[4] = { fc1_w,     fc1_wt,     DMODEL, 2048,   704 };
        segs.s[5] = { fc2_w,     fc2_wt,     2048,   DMODEL, 1216 };
        wcvt_all_k<<<1728, blk, 0, stream>>>(segs);
    }

    // --- adapter: h0 = x @ adapter_w + b ---
    mgemm_k<64, 64, 2, 2, 4><<<dim3(NTOK / 64, DMODEL / 64), blk, 0, stream>>>(
        xb, adapter_wt, adapter_b, nullptr, h0, h0b, nullptr, NTOK, DMODEL, EMB);
    // --- h = h0 + relu(h0 @ res_w + b) ---
    mgemm_k<64, 64, 2, 2, 1><<<dim3(NTOK / 64, DMODEL / 64), blk, 0, stream>>>(
        h0b, res_wt, res_b, h0, h, nullptr, nullptr, NTOK, DMODEL, DMODEL);

    // dsel: h0 now dead until lnf
    dsel_k<<<NTOK, blk, 0, stream>>>(distance, indices, dsel);

    for (int l = 0; l < NLAYER; l++) {
        ln_k<1><<<NTOK, blk, 0, stream>>>(h, ln1_g + l * DMODEL, ln1_b + l * DMODEL, lnb, 1e-5f);
        mgemm_k<64, 128, 2, 2, 5><<<dim3(NTOK / 64, 1536 / 128), blk, 0, stream>>>(
            lnb, qkv_wt + (size_t)l * 1536 * DMODEL, qkv_b + l * 1536, nullptr,
            nullptr, qkvbb, kn, NTOK, 1536, DMODEL);
        attn_k<<<ATTN_BLOCKS, blk, 0, stream>>>(qkvbb, kn, indices, dsel, lam, xob, l);
        mgemm_k<64, 64, 2, 2, 3><<<dim3(NTOK / 64, DMODEL / 64), blk, 0, stream>>>(
            xob, proj_wt + (size_t)l * DMODEL * DMODEL, proj_b + l * DMODEL, h,
            h, nullptr, nullptr, NTOK, DMODEL, DMODEL);
        ln_k<1><<<NTOK, blk, 0, stream>>>(h, ln2_g + l * DMODEL, ln2_b + l * DMODEL, lnb, 1e-5f);
        mgemm_k<64, 128, 2, 2, 2><<<dim3(NTOK / 64, 2048 / 128), blk, 0, stream>>>(
            lnb, fc1_wt + (size_t)l * 2048 * DMODEL, fc1_b + l * 2048, nullptr,
            nullptr, fc1b, nullptr, NTOK, 2048, DMODEL);
        mgemm_k<64, 64, 2, 2, 3><<<dim3(NTOK / 64, DMODEL / 64), blk, 0, stream>>>(
            fc1b, fc2_wt + (size_t)l * DMODEL * 2048, fc2_b + l * DMODEL, h,
            h, nullptr, nullptr, NTOK, DMODEL, 2048);
    }

    ln_k<0><<<NTOK, blk, 0, stream>>>(h, lnf_g, lnf_b, h0, 1e-6f);
    colpart_k<<<256, 512, 0, stream>>>(h0, part);
    finhead_k<<<1, 512, 0, stream>>>(part, head_w, head_b, out);
}

// Round 12
// 330.232 us; speedup vs baseline: 1.4736x; 1.0722x over previous
//
#include <hip/hip_runtime.h>
#include <hip/hip_bf16.h>

#define NTOK 4096
#define EMB 1024
#define DMODEL 512
#define NHEAD 8
#define NLAYER 2
#define NCLS 2
#define KMAX 160

typedef __attribute__((ext_vector_type(8))) short bf16x8;
typedef __attribute__((ext_vector_type(4))) float f32x4;

__device__ inline unsigned short f2b(float f) {
    unsigned u = __float_as_uint(f);
    u = u + 0x7FFFu + ((u >> 16) & 1u);
    return (unsigned short)(u >> 16);
}
__device__ inline float b2f(unsigned short s) {
    return __uint_as_float((unsigned)s << 16);
}

// v_dot2_f32_bf16: d = a.lo*b.lo + a.hi*b.hi + c  (packed bf16 pairs)
__device__ inline float dot2bf(unsigned a, unsigned b, float c) {
    float d;
    asm("v_dot2_f32_bf16 %0, %1, %2, %3" : "=v"(d) : "v"(a), "v"(b), "v"(c));
    return d;
}

__device__ inline float wsum(float v) {
    for (int o = 32; o > 0; o >>= 1) v += __shfl_xor(v, o, 64);
    return v;
}
__device__ inline float wmax(float v) {
    for (int o = 32; o > 0; o >>= 1) v = fmaxf(v, __shfl_xor(v, o, 64));
    return v;
}

// async global->LDS, 16 B per lane. dest must be wave-uniform base + lane*16.
typedef __attribute__((address_space(3))) unsigned lds_u32_t;
typedef __attribute__((address_space(1))) const unsigned glb_u32_t;
__device__ inline void gload16(const void* g, void* l) {
    __builtin_amdgcn_global_load_lds((glb_u32_t*)(unsigned long long)g,
                                     (lds_u32_t*)(unsigned)(unsigned long long)l,
                                     16, 0, 0);
}

// Balanced head->XCD schedule: work blocks of 4 rows, 1024 blocks/head.
__device__ const int g_s0cnt[8]  = {576, 448, 720, 144, 365, 490, 460, 159};
__device__ const int g_s0h[8]    = {7, 7, 6, 6, 5, 4, 3, 2};
__device__ const int g_s0base[8] = {0, 576, 160, 880, 659, 534, 564, 865};
__device__ const int g_s1cnt[8]  = {0, 160, 0, 659, 534, 564, 865, 1024};
__device__ const int g_s1h[8]    = {0, 6, 0, 5, 4, 3, 2, 1};
#define ATTN_BLOCKS (2207 * 8)

// ---------------- prep: all 6 weight groups transposed+cvt AND x->bf16, 1 dispatch ----
struct WSeg { const float* src; unsigned short* dst; int K; int N; int tile0; };
struct Prep { WSeg s[6]; const float* x; unsigned short* xb; int xtile0; };

__global__ __launch_bounds__(256) void prep_k(Prep p)
{
    __shared__ unsigned short tile[64][72];
    int t0 = blockIdx.x;
    if (t0 >= p.xtile0) {
        int i = ((t0 - p.xtile0) * 256 + threadIdx.x) * 8;
        float4 a = *(const float4*)(p.x + i);
        float4 b = *(const float4*)(p.x + i + 4);
        unsigned short o[8];
        o[0] = f2b(a.x); o[1] = f2b(a.y); o[2] = f2b(a.z); o[3] = f2b(a.w);
        o[4] = f2b(b.x); o[5] = f2b(b.y); o[6] = f2b(b.z); o[7] = f2b(b.w);
        *(uint4*)(p.xb + i) = *(const uint4*)o;
        return;
    }
    int si = 0;
#pragma unroll
    for (int i = 1; i < 6; i++) if (t0 >= p.s[i].tile0) si = i;
    const float* src0 = p.s[si].src;
    unsigned short* dst0 = p.s[si].dst;
    int K = p.s[si].K, N = p.s[si].N;
    int lt = t0 - p.s[si].tile0;
    int tx = K >> 6, ty = N >> 6;
    int per = tx * ty;
    int l = lt / per, rr = lt - l * per;
    int k0 = (rr % tx) << 6, n0 = (rr / tx) << 6;
    size_t ls = (size_t)K * N * l;
    const float* Wl = src0 + ls;
    unsigned short* Wtl = dst0 + ls;

    int t = threadIdx.x;
    int kl = t >> 2, nb = (t & 3) * 16;
    const float* src = Wl + (size_t)(k0 + kl) * N + n0 + nb;
#pragma unroll
    for (int i = 0; i < 4; i++) {
        float4 v = *(const float4*)(src + 4 * i);
        tile[nb + 4 * i + 0][kl] = f2b(v.x);
        tile[nb + 4 * i + 1][kl] = f2b(v.y);
        tile[nb + 4 * i + 2][kl] = f2b(v.z);
        tile[nb + 4 * i + 3][kl] = f2b(v.w);
    }
    __syncthreads();
    int nl = t >> 2, ks = (t & 3) * 16;
    unsigned short* dst = Wtl + (size_t)(n0 + nl) * K + k0 + ks;
    *(uint4*)dst = *(const uint4*)&tile[nl][ks];
    *(uint4*)(dst + 8) = *(const uint4*)&tile[nl][ks + 8];
}

// ---------------- dsel[n][k] = distance[n][indices[n][k]] ----------------
__global__ __launch_bounds__(256) void dsel_k(const float* __restrict__ distance,
                                              const int* __restrict__ indices,
                                              float* __restrict__ dsel)
{
    int n = blockIdx.x, t = threadIdx.x;
    if (t < KMAX) {
        int idx = indices[(size_t)n * KMAX + t];
        dsel[(size_t)n * KMAX + t] = distance[(size_t)n * NTOK + idx];
    }
}

// ---------------- MFMA GEMM: BK=64, double-buffered, XOR-swizzled LDS ----------------
// Swizzle: logical 16B chunk lc of row r stored at phys chunk lc ^ (r&7).
// MODE 5 (qkv) additionally writes kn[row][head] (requires SN==64).
template <int BM, int BN, int WM, int WN, int MODE>
__global__ __launch_bounds__(256) void mgemm_k(
    const unsigned short* __restrict__ A, const unsigned short* __restrict__ Wt,
    const float* __restrict__ bias, const float* __restrict__ resid,
    float* __restrict__ Cf, unsigned short* __restrict__ Cb,
    float* __restrict__ knout,
    int M, int N, int K)
{
    constexpr int SM = BM / WM;
    constexpr int SN = BN / WN;
    constexpr int MR = SM / 16;
    constexpr int NR = SN / 16;

    __shared__ unsigned short Asl[2][BM * 64];
    __shared__ unsigned short Bsl[2][BN * 64];

    int tid = threadIdx.x;
    int bm = blockIdx.x * BM, bn = blockIdx.y * BN;
    int lane = tid & 63, wid = tid >> 6;
    int wm = wid / WN, wn = wid % WN;
    int l15 = lane & 15, l4 = lane >> 4;

    f32x4 acc[MR][NR] = {};

    auto stage = [&](int buf, int k0) {
#pragma unroll
        for (int i = 0; i < BM / 32; i++) {
            int ci = i * 256 + tid;
            int r = ci >> 3, c = ci & 7;
            gload16(A + (size_t)(bm + r) * K + k0 + ((c ^ (r & 7)) * 8),
                    &Asl[buf][ci * 8]);
        }
#pragma unroll
        for (int i = 0; i < BN / 32; i++) {
            int ci = i * 256 + tid;
            int r = ci >> 3, c = ci & 7;
            gload16(Wt + (size_t)(bn + r) * K + k0 + ((c ^ (r & 7)) * 8),
                    &Bsl[buf][ci * 8]);
        }
    };

    int nt = K / 64;
    stage(0, 0);
    __syncthreads();
    int cur = 0;
    for (int t = 0; t < nt; t++) {
        if (t + 1 < nt) stage(cur ^ 1, (t + 1) * 64);
#pragma unroll
        for (int ks = 0; ks < 2; ks++) {
            bf16x8 af[MR], bfr[NR];
#pragma unroll
            for (int mr = 0; mr < MR; mr++) {
                int ar = wm * SM + mr * 16 + l15;
                af[mr] = *(const bf16x8*)&Asl[cur][ar * 64 + ((((ks << 2) | l4) ^ (ar & 7)) * 8)];
            }
#pragma unroll
            for (int nr = 0; nr < NR; nr++) {
                int br = wn * SN + nr * 16 + l15;
                bfr[nr] = *(const bf16x8*)&Bsl[cur][br * 64 + ((((ks << 2) | l4) ^ (br & 7)) * 8)];
            }
#pragma unroll
            for (int mr = 0; mr < MR; mr++)
#pragma unroll
                for (int nr = 0; nr < NR; nr++)
                    acc[mr][nr] = __builtin_amdgcn_mfma_f32_16x16x32_bf16(af[mr], bfr[nr], acc[mr][nr], 0, 0, 0);
        }
        __syncthreads();
        cur ^= 1;
    }

#pragma unroll
    for (int mr = 0; mr < MR; mr++) {
#pragma unroll
        for (int nr = 0; nr < NR; nr++) {
            int col = bn + wn * SN + nr * 16 + l15;
            float bcol = bias[col];
#pragma unroll
            for (int r = 0; r < 4; r++) {
                int row = bm + wm * SM + mr * 16 + l4 * 4 + r;
                size_t off = (size_t)row * N + col;
                float v = acc[mr][nr][r] + bcol;
                if (MODE == 0) {
                    Cf[off] = v;
                } else if (MODE == 1) {
                    Cf[off] = resid[off] + fmaxf(v, 0.f);
                } else if (MODE == 2) {
                    float t3 = tanhf(0.7978845608028654f * (v + 0.044715f * v * v * v));
                    Cb[off] = f2b(0.5f * v * (1.f + t3));
                } else if (MODE == 3) {
                    Cf[off] = resid[off] + v;
                } else if (MODE == 4) {
                    Cf[off] = v;
                    Cb[off] = f2b(v);
                } else {
                    Cb[off] = f2b(v);
                }
            }
        }
    }

    // fused kn for the K region of qkv output (cols 512..1024)
    if (MODE == 5) {
        int cbase = bn + wn * SN;
        if (cbase >= 512 && cbase < 1024) {
            int hh = (cbase - 512) >> 6;
#pragma unroll
            for (int mr = 0; mr < MR; mr++) {
#pragma unroll
                for (int r = 0; r < 4; r++) {
                    float p = 0.f;
#pragma unroll
                    for (int nr = 0; nr < NR; nr++) {
                        float v = acc[mr][nr][r] + bias[cbase + nr * 16 + l15];
                        p += v * v;
                    }
                    p += __shfl_xor(p, 1, 64);
                    p += __shfl_xor(p, 2, 64);
                    p += __shfl_xor(p, 4, 64);
                    p += __shfl_xor(p, 8, 64);
                    if (l15 == 0) {
                        int row = bm + wm * SM + mr * 16 + l4 * 4 + r;
                        knout[row * NHEAD + hh] = p;
                    }
                }
            }
        }
    }
}

// ---------------- LayerNorm over D=512, one row per block ----------------
template <int OUTB>
__global__ __launch_bounds__(256) void ln_k(
    const float* __restrict__ X, const float* __restrict__ g,
    const float* __restrict__ bta, void* __restrict__ Yv, float eps)
{
    int row = blockIdx.x;
    int tid = threadIdx.x;
    const float* xr = X + (size_t)row * DMODEL;
    float v0 = xr[tid], v1 = xr[tid + 256];
    __shared__ float red[8];
    float s = wsum(v0 + v1);
    int wid = tid >> 6, lane = tid & 63;
    if (lane == 0) red[wid] = s;
    __syncthreads();
    float m = (red[0] + red[1] + red[2] + red[3]) * (1.f / DMODEL);
    float d0 = v0 - m, d1 = v1 - m;
    float sq = wsum(d0 * d0 + d1 * d1);
    if (lane == 0) red[4 + wid] = sq;
    __syncthreads();
    float var = (red[4] + red[5] + red[6] + red[7]) * (1.f / DMODEL);
    float rs = 1.0f / sqrtf(var + eps);
    float y0 = d0 * rs * g[tid] + bta[tid];
    float y1 = d1 * rs * g[tid + 256] + bta[tid + 256];
    if (OUTB) {
        unsigned short* Y = (unsigned short*)Yv;
        Y[(size_t)row * DMODEL + tid] = f2b(y0);
        Y[(size_t)row * DMODEL + tid + 256] = f2b(y1);
    } else {
        float* Y = (float*)Yv;
        Y[(size_t)row * DMODEL + tid] = y0;
        Y[(size_t)row * DMODEL + tid + 256] = y1;
    }
}

// ---------------- gathered attention, bf16 qkv, balanced head->XCD schedule --------
// Phase A: 4 lanes per neighbor, 2-deep pipelined coalesced K loads, dot2.
// Phase B: lane-per-neighbor finalization (kn gather, decay approx -sp*d) + softmax.
// Phase C: 8 lanes per neighbor, uint4 V loads.
__global__ __launch_bounds__(256) void attn_k(
    const unsigned short* __restrict__ qkv,   // [n][1536] bf16
    const float* __restrict__ kn,             // [n][8]
    const int* __restrict__ indices, const float* __restrict__ dsel,
    const float* __restrict__ lam, unsigned short* __restrict__ xo, int layer)
{
    int xcd = blockIdx.x & 7;
    int t = blockIdx.x >> 3;
    int hh, blk;
    int c0 = g_s0cnt[xcd];
    if (t < c0) {
        hh = g_s0h[xcd]; blk = g_s0base[xcd] + t;
    } else {
        t -= c0;
        int c1 = g_s1cnt[xcd];
        if (t < c1) {
            hh = g_s1h[xcd]; blk = t;
        } else if (xcd == 7 && t - c1 < 1024) {
            hh = 0; blk = t - c1;
        } else {
            return;
        }
    }

    int wid = threadIdx.x >> 6, lane = threadIdx.x & 63;
    int n = blk * 4 + wid;
    int Kh = 32 + 16 * hh + (hh == 7 ? 16 : 0);   // 32..160, multiples of 16

    __shared__ __align__(16) unsigned qsp[4][32];   // q as packed bf16 pairs
    __shared__ float asc[4][KMAX];
    __shared__ int   sidx[4][KMAX];

    const unsigned short* qrow = qkv + (size_t)n * 1536 + hh * 64;
    float qd = b2f(qrow[lane]);
    if (lane < 32) qsp[wid][lane] = ((const unsigned*)qrow)[lane];
    float qn2 = wsum(qd * qd);
    float sp = log1pf(expf(lam[layer * NHEAD + hh]));

    const int* irow = indices + (size_t)n * KMAX;
    const float* drow = dsel + (size_t)n * KMAX;

    // ---- Phase A: 16 neighbors/iter, 4 lanes each; dot2; 2-deep pipeline ----
    int sub = lane & 3, grp = lane >> 2;
    const uint4* qp = (const uint4*)&qsp[wid][0];
    uint4 qa = qp[sub], qb = qp[4 + sub];

    int iters = Kh >> 4;
    int idxn = irow[grp];
    const uint4* krn = (const uint4*)(qkv + (size_t)idxn * 1536 + 512 + hh * 64);
    uint4 kan = krn[sub], kbn = krn[4 + sub];
    for (int it = 0; it < iters; it++) {
        int idxc = idxn;
        uint4 ka = kan, kb = kbn;
        if (it + 1 < iters) {
            idxn = irow[(it + 1) * 16 + grp];
            const uint4* kr = (const uint4*)(qkv + (size_t)idxn * 1536 + 512 + hh * 64);
            kan = kr[sub]; kbn = kr[4 + sub];
        }
        float d0 = 0.f, d1 = 0.f, d2 = 0.f, d3 = 0.f;
        d0 = dot2bf(ka.x, qa.x, d0); d1 = dot2bf(ka.y, qa.y, d1);
        d2 = dot2bf(ka.z, qa.z, d2); d3 = dot2bf(ka.w, qa.w, d3);
        d0 = dot2bf(kb.x, qb.x, d0); d1 = dot2bf(kb.y, qb.y, d1);
        d2 = dot2bf(kb.z, qb.z, d2); d3 = dot2bf(kb.w, qb.w, d3);
        float dp = (d0 + d1) + (d2 + d3);
        dp += __shfl_xor(dp, 1, 64);
        dp += __shfl_xor(dp, 2, 64);
        if (sub == 0) {
            int kk = it * 16 + grp;
            asc[wid][kk] = dp;
            sidx[wid][kk] = idxc;
        }
    }

    // ---- Phase B: finalize scores + softmax ----
    // decay approx: log(exp(-sp*d)+1e-6) ~= -sp*d  (error <0.017 only for
    // neighbors >=9 units below max -> weight <1e-4; output error ~1e-4)
    float s0 = -1e30f, s1 = -1e30f, s2 = -1e30f;
    {
        int kk = lane;
        if (kk < Kh) {
            float knv = kn[sidx[wid][kk] * NHEAD + hh];
            s0 = (asc[wid][kk] - 0.5f * (qn2 + knv)) * 0.125f - sp * drow[kk];
        }
        kk = lane + 64;
        if (kk < Kh) {
            float knv = kn[sidx[wid][kk] * NHEAD + hh];
            s1 = (asc[wid][kk] - 0.5f * (qn2 + knv)) * 0.125f - sp * drow[kk];
        }
        kk = lane + 128;
        if (kk < Kh) {
            float knv = kn[sidx[wid][kk] * NHEAD + hh];
            s2 = (asc[wid][kk] - 0.5f * (qn2 + knv)) * 0.125f - sp * drow[kk];
        }
    }
    float mx = wmax(fmaxf(fmaxf(s0, s1), s2));
    float e0 = (s0 > -1e29f) ? expf(s0 - mx) : 0.f;
    float e1 = (s1 > -1e29f) ? expf(s1 - mx) : 0.f;
    float e2 = (s2 > -1e29f) ? expf(s2 - mx) : 0.f;
    float se = wsum(e0 + e1 + e2);
    float inv = 1.f / se;
    if (lane < Kh)       asc[wid][lane]       = e0 * inv;
    if (lane + 64 < Kh)  asc[wid][lane + 64]  = e1 * inv;
    if (lane + 128 < Kh) asc[wid][lane + 128] = e2 * inv;

    // ---- Phase C: PV, 8 lanes per neighbor (lane = g*8+q), uint4 V loads ----
    int g = lane >> 3, q = lane & 7;
    const uint4* vb = (const uint4*)(qkv + 1024 + hh * 64 + q * 8);  // +idx*192 per row
    float a8[8] = {};
    int k0 = 0;
    int kmain = Kh & ~31;
    for (; k0 < kmain; k0 += 32) {
        int ii[4]; float aa[4]; uint4 vv[4];
#pragma unroll
        for (int u = 0; u < 4; u++) {
            int kk = k0 + u * 8 + g;
            ii[u] = sidx[wid][kk];
            aa[u] = asc[wid][kk];
        }
#pragma unroll
        for (int u = 0; u < 4; u++) vv[u] = vb[(size_t)ii[u] * 192];
#pragma unroll
        for (int u = 0; u < 4; u++) {
            const unsigned short* vp = (const unsigned short*)&vv[u];
#pragma unroll
            for (int d = 0; d < 8; d++) a8[d] += aa[u] * b2f(vp[d]);
        }
    }
    if (Kh & 16) {
        int ii[2]; float aa[2]; uint4 vv[2];
#pragma unroll
        for (int u = 0; u < 2; u++) {
            int kk = k0 + u * 8 + g;
            ii[u] = sidx[wid][kk];
            aa[u] = asc[wid][kk];
        }
#pragma unroll
        for (int u = 0; u < 2; u++) vv[u] = vb[(size_t)ii[u] * 192];
#pragma unroll
        for (int u = 0; u < 2; u++) {
            const unsigned short* vp = (const unsigned short*)&vv[u];
#pragma unroll
            for (int d = 0; d < 8; d++) a8[d] += aa[u] * b2f(vp[d]);
        }
    }
#pragma unroll
    for (int d = 0; d < 8; d++) {
        a8[d] += __shfl_xor(a8[d], 8, 64);
        a8[d] += __shfl_xor(a8[d], 16, 64);
        a8[d] += __shfl_xor(a8[d], 32, 64);
    }
    if (lane < 8) {
        unsigned o[4];
#pragma unroll
        for (int p = 0; p < 4; p++)
            o[p] = ((unsigned)f2b(a8[2 * p + 1]) << 16) | (unsigned)f2b(a8[2 * p]);
        *(uint4*)(xo + (size_t)n * DMODEL + hh * 64 + lane * 8) = *(uint4*)o;
    }
}

// ---------------- column partial sums ----------------
__global__ __launch_bounds__(512) void colpart_k(const float* __restrict__ Y, float* __restrict__ part)
{
    int c = threadIdx.x;
    int blk = blockIdx.x;
    const float* p = Y + (size_t)blk * 16 * DMODEL + c;
    float s = 0.f;
#pragma unroll
    for (int r = 0; r < 16; r++) s += p[r * DMODEL];
    part[blk * DMODEL + c] = s;
}

// ---------------- finish mean + head GEMV ----------------
__global__ __launch_bounds__(512) void finhead_k(
    const float* __restrict__ part, const float* __restrict__ head_w,
    const float* __restrict__ head_b, float* __restrict__ out)
{
    __shared__ float mv[DMODEL];
    int c = threadIdx.x;
    float s = 0.f;
    for (int i = 0; i < 256; i++) s += part[i * DMODEL + c];
    mv[c] = s * (1.f / NTOK);
    __syncthreads();
    if (c < 64) {
        float a0 = 0.f, a1 = 0.f;
        for (int d = c; d < DMODEL; d += 64) {
            float m = mv[d];
            a0 += m * head_w[d * NCLS + 0];
            a1 += m * head_w[d * NCLS + 1];
        }
        a0 = wsum(a0);
        a1 = wsum(a1);
        if (c == 0) { out[0] = a0 + head_b[0]; out[1] = a1 + head_b[1]; }
    }
}

extern "C" void kernel_launch(void* const* d_in, const int* in_sizes, int n_in,
                              void* d_out, int out_size, void* d_ws, size_t ws_size,
                              hipStream_t stream)
{
    const float* x        = (const float*)d_in[0];
    const float* distance = (const float*)d_in[1];
    const int*   indices  = (const int*)d_in[2];
    const float* adapter_w = (const float*)d_in[5];
    const float* adapter_b = (const float*)d_in[6];
    const float* res_w     = (const float*)d_in[7];
    const float* res_b     = (const float*)d_in[8];
    const float* ln1_g     = (const float*)d_in[9];
    const float* ln1_b     = (const float*)d_in[10];
    const float* qkv_w     = (const float*)d_in[11];
    const float* qkv_b     = (const float*)d_in[12];
    const float* proj_w    = (const float*)d_in[13];
    const float* proj_b    = (const float*)d_in[14];
    const float* ln2_g     = (const float*)d_in[15];
    const float* ln2_b     = (const float*)d_in[16];
    const float* fc1_w     = (const float*)d_in[17];
    const float* fc1_b     = (const float*)d_in[18];
    const float* fc2_w     = (const float*)d_in[19];
    const float* fc2_b     = (const float*)d_in[20];
    const float* lam       = (const float*)d_in[21];
    const float* lnf_g     = (const float*)d_in[22];
    const float* lnf_b     = (const float*)d_in[23];
    const float* head_w    = (const float*)d_in[24];
    const float* head_b    = (const float*)d_in[25];
    float* out = (float*)d_out;

    char* wsb = (char*)d_ws;
    float* h   = (float*)(wsb);                         // 8 MB
    float* h0  = (float*)(wsb + (8u << 20));            // 8 MB; dead during layers -> dsel
    float* dsel = (float*)(wsb + (8u << 20));           // 2.6 MB
    char* shared = wsb + (16u << 20);                   // 24 MB shared region
    unsigned short* xb    = (unsigned short*)shared;                // 8 MB (dead after adapter)
    unsigned short* qkvbb = (unsigned short*)shared;                // 12 MB bf16
    unsigned short* fc1b  = (unsigned short*)shared;                // 16 MB (after attn)
    unsigned short* adapter_wt = (unsigned short*)(shared + (8u << 20));  // 1 MB
    unsigned short* res_wt     = (unsigned short*)(shared + (9u << 20));  // 0.5 MB
    unsigned short* lnb  = (unsigned short*)(wsb + (40u << 20));    // 4 MB (also h0b)
    unsigned short* h0b  = lnb;
    unsigned short* xob  = (unsigned short*)(wsb + (44u << 20));    // 4 MB
    unsigned short* qkv_wt = (unsigned short*)(wsb + (48u << 20));  // 3 MB
    unsigned short* proj_wt = (unsigned short*)(wsb + (51u << 20)); // 1 MB
    unsigned short* fc1_wt  = (unsigned short*)(wsb + (52u << 20)); // 4 MB
    unsigned short* fc2_wt  = (unsigned short*)(wsb + (56u << 20)); // 4 MB
    float* kn   = (float*)(wsb + (60u << 20));                      // 128 KB
    float* part = (float*)(wsb + (60u << 20) + (1u << 18));         // 512 KB

    dim3 blk(256);

    // --- prep: all weight conversions + x->bf16 in ONE dispatch ---
    {
        Prep p;
        p.s[0] = { adapter_w, adapter_wt, EMB,    DMODEL, 0 };
        p.s[1] = { res_w,     res_wt,     DMODEL, DMODEL, 128 };
        p.s[2] = { qkv_w,     qkv_wt,     DMODEL, 1536,   192 };
        p.s[3] = { proj_w,    proj_wt,    DMODEL, DMODEL, 576 };
        p.s[4] = { fc1_w,     fc1_wt,     DMODEL, 2048,   704 };
        p.s[5] = { fc2_w,     fc2_wt,     2048,   DMODEL, 1216 };
        p.x = x; p.xb = xb; p.xtile0 = 1728;
        prep_k<<<1728 + (NTOK * EMB) / 2048, blk, 0, stream>>>(p);
    }

    // --- adapter: h0 = x @ adapter_w + b ---
    mgemm_k<64, 64, 2, 2, 4><<<dim3(NTOK / 64, DMODEL / 64), blk, 0, stream>>>(
        xb, adapter_wt, adapter_b, nullptr, h0, h0b, nullptr, NTOK, DMODEL, EMB);
    // --- h = h0 + relu(h0 @ res_w + b) ---
    mgemm_k<64, 64, 2, 2, 1><<<dim3(NTOK / 64, DMODEL / 64), blk, 0, stream>>>(
        h0b, res_wt, res_b, h0, h, nullptr, nullptr, NTOK, DMODEL, DMODEL);

    // dsel: h0 now dead until lnf
    dsel_k<<<NTOK, blk, 0, stream>>>(distance, indices, dsel);

    for (int l = 0; l < NLAYER; l++) {
        ln_k<1><<<NTOK, blk, 0, stream>>>(h, ln1_g + l * DMODEL, ln1_b + l * DMODEL, lnb, 1e-5f);
        mgemm_k<64, 128, 2, 2, 5><<<dim3(NTOK / 64, 1536 / 128), blk, 0, stream>>>(
            lnb, qkv_wt + (size_t)l * 1536 * DMODEL, qkv_b + l * 1536, nullptr,
            nullptr, qkvbb, kn, NTOK, 1536, DMODEL);
        attn_k<<<ATTN_BLOCKS, blk, 0, stream>>>(qkvbb, kn, indices, dsel, lam, xob, l);
        mgemm_k<64, 64, 2, 2, 3><<<dim3(NTOK / 64, DMODEL / 64), blk, 0, stream>>>(
            xob, proj_wt + (size_t)l * DMODEL * DMODEL, proj_b + l * DMODEL, h,
            h, nullptr, nullptr, NTOK, DMODEL, DMODEL);
        ln_k<1><<<NTOK, blk, 0, stream>>>(h, ln2_g + l * DMODEL, ln2_b + l * DMODEL, lnb, 1e-5f);
        mgemm_k<64, 128, 2, 2, 2><<<dim3(NTOK / 64, 2048 / 128), blk, 0, stream>>>(
            lnb, fc1_wt + (size_t)l * 2048 * DMODEL, fc1_b + l * 2048, nullptr,
            nullptr, fc1b, nullptr, NTOK, 2048, DMODEL);
        mgemm_k<64, 64, 2, 2, 3><<<dim3(NTOK / 64, DMODEL / 64), blk, 0, stream>>>(
            fc1b, fc2_wt + (size_t)l * DMODEL * 2048, fc2_b + l * DMODEL, h,
            h, nullptr, nullptr, NTOK, DMODEL, 2048);
    }

    ln_k<0><<<NTOK, blk, 0, stream>>>(h, lnf_g, lnf_b, h0, 1e-6f);
    colpart_k<<<256, 512, 0, stream>>>(h0, part);
    finhead_k<<<1, 512, 0, stream>>>(part, head_w, head_b, out);
}

// Round 13
// 315.868 us; speedup vs baseline: 1.5406x; 1.0455x over previous
//
#include <hip/hip_runtime.h>
#include <hip/hip_bf16.h>

#define NTOK 4096
#define EMB 1024
#define DMODEL 512
#define NHEAD 8
#define NLAYER 2
#define NCLS 2
#define KMAX 160

typedef __attribute__((ext_vector_type(8))) short bf16x8;
typedef __attribute__((ext_vector_type(4))) float f32x4;

__device__ inline unsigned short f2b(float f) {
    unsigned u = __float_as_uint(f);
    u = u + 0x7FFFu + ((u >> 16) & 1u);
    return (unsigned short)(u >> 16);
}
__device__ inline float b2f(unsigned short s) {
    return __uint_as_float((unsigned)s << 16);
}

// v_dot2_f32_bf16: d = a.lo*b.lo + a.hi*b.hi + c  (packed bf16 pairs)
__device__ inline float dot2bf(unsigned a, unsigned b, float c) {
    float d;
    asm("v_dot2_f32_bf16 %0, %1, %2, %3" : "=v"(d) : "v"(a), "v"(b), "v"(c));
    return d;
}

__device__ inline float wsum(float v) {
    for (int o = 32; o > 0; o >>= 1) v += __shfl_xor(v, o, 64);
    return v;
}
__device__ inline float wmax(float v) {
    for (int o = 32; o > 0; o >>= 1) v = fmaxf(v, __shfl_xor(v, o, 64));
    return v;
}

// async global->LDS, 16 B per lane. dest must be wave-uniform base + lane*16.
typedef __attribute__((address_space(3))) unsigned lds_u32_t;
typedef __attribute__((address_space(1))) const unsigned glb_u32_t;
__device__ inline void gload16(const void* g, void* l) {
    __builtin_amdgcn_global_load_lds((glb_u32_t*)(unsigned long long)g,
                                     (lds_u32_t*)(unsigned)(unsigned long long)l,
                                     16, 0, 0);
}

// Head->XCD schedule rebalanced with per-wave fixed cost:
// weight per 4-row block = 4*(Kh + 50). Per-XCD weighted load 573.3-573.8k (+-0.1%).
// Each XCD touches <=2 heads (<=2MB K+V working set, fits 4MB L2).
__device__ const int g_s0cnt[8]  = {682, 342, 622, 822, 954, 993, 899, 607};
__device__ const int g_s0h[8]    = {7, 7, 6, 5, 4, 3, 2, 1};
__device__ const int g_s0base[8] = {0, 682, 402, 202, 70, 31, 125, 417};
__device__ const int g_s1cnt[8]  = {0, 402, 202, 70, 31, 125, 417, 1024};
__device__ const int g_s1h[8]    = {0, 6, 5, 4, 3, 2, 1, 0};
#define ATTN_BLOCKS (1631 * 8)

// ---------------- prep: all 6 weight groups transposed+cvt AND x->bf16, 1 dispatch ----
struct WSeg { const float* src; unsigned short* dst; int K; int N; int tile0; };
struct Prep { WSeg s[6]; const float* x; unsigned short* xb; int xtile0; };

__global__ __launch_bounds__(256) void prep_k(Prep p)
{
    __shared__ unsigned short tile[64][72];
    int t0 = blockIdx.x;
    if (t0 >= p.xtile0) {
        int i = ((t0 - p.xtile0) * 256 + threadIdx.x) * 8;
        float4 a = *(const float4*)(p.x + i);
        float4 b = *(const float4*)(p.x + i + 4);
        unsigned short o[8];
        o[0] = f2b(a.x); o[1] = f2b(a.y); o[2] = f2b(a.z); o[3] = f2b(a.w);
        o[4] = f2b(b.x); o[5] = f2b(b.y); o[6] = f2b(b.z); o[7] = f2b(b.w);
        *(uint4*)(p.xb + i) = *(const uint4*)o;
        return;
    }
    int si = 0;
#pragma unroll
    for (int i = 1; i < 6; i++) if (t0 >= p.s[i].tile0) si = i;
    const float* src0 = p.s[si].src;
    unsigned short* dst0 = p.s[si].dst;
    int K = p.s[si].K, N = p.s[si].N;
    int lt = t0 - p.s[si].tile0;
    int tx = K >> 6, ty = N >> 6;
    int per = tx * ty;
    int l = lt / per, rr = lt - l * per;
    int k0 = (rr % tx) << 6, n0 = (rr / tx) << 6;
    size_t ls = (size_t)K * N * l;
    const float* Wl = src0 + ls;
    unsigned short* Wtl = dst0 + ls;

    int t = threadIdx.x;
    int kl = t >> 2, nb = (t & 3) * 16;
    const float* src = Wl + (size_t)(k0 + kl) * N + n0 + nb;
#pragma unroll
    for (int i = 0; i < 4; i++) {
        float4 v = *(const float4*)(src + 4 * i);
        tile[nb + 4 * i + 0][kl] = f2b(v.x);
        tile[nb + 4 * i + 1][kl] = f2b(v.y);
        tile[nb + 4 * i + 2][kl] = f2b(v.z);
        tile[nb + 4 * i + 3][kl] = f2b(v.w);
    }
    __syncthreads();
    int nl = t >> 2, ks = (t & 3) * 16;
    unsigned short* dst = Wtl + (size_t)(n0 + nl) * K + k0 + ks;
    *(uint4*)dst = *(const uint4*)&tile[nl][ks];
    *(uint4*)(dst + 8) = *(const uint4*)&tile[nl][ks + 8];
}

// ---------------- dsel[n][k] = distance[n][indices[n][k]] ----------------
__global__ __launch_bounds__(256) void dsel_k(const float* __restrict__ distance,
                                              const int* __restrict__ indices,
                                              float* __restrict__ dsel)
{
    int n = blockIdx.x, t = threadIdx.x;
    if (t < KMAX) {
        int idx = indices[(size_t)n * KMAX + t];
        dsel[(size_t)n * KMAX + t] = distance[(size_t)n * NTOK + idx];
    }
}

// ---------------- MFMA GEMM: BK=64, double-buffered, XOR-swizzled LDS ----------------
// Swizzle: logical 16B chunk lc of row r stored at phys chunk lc ^ (r&7).
// MODE 5 (qkv) additionally writes kn[row][head] (requires SN==64).
template <int BM, int BN, int WM, int WN, int MODE>
__global__ __launch_bounds__(256) void mgemm_k(
    const unsigned short* __restrict__ A, const unsigned short* __restrict__ Wt,
    const float* __restrict__ bias, const float* __restrict__ resid,
    float* __restrict__ Cf, unsigned short* __restrict__ Cb,
    float* __restrict__ knout,
    int M, int N, int K)
{
    constexpr int SM = BM / WM;
    constexpr int SN = BN / WN;
    constexpr int MR = SM / 16;
    constexpr int NR = SN / 16;

    __shared__ unsigned short Asl[2][BM * 64];
    __shared__ unsigned short Bsl[2][BN * 64];

    int tid = threadIdx.x;
    int bm = blockIdx.x * BM, bn = blockIdx.y * BN;
    int lane = tid & 63, wid = tid >> 6;
    int wm = wid / WN, wn = wid % WN;
    int l15 = lane & 15, l4 = lane >> 4;

    f32x4 acc[MR][NR] = {};

    auto stage = [&](int buf, int k0) {
#pragma unroll
        for (int i = 0; i < BM / 32; i++) {
            int ci = i * 256 + tid;
            int r = ci >> 3, c = ci & 7;
            gload16(A + (size_t)(bm + r) * K + k0 + ((c ^ (r & 7)) * 8),
                    &Asl[buf][ci * 8]);
        }
#pragma unroll
        for (int i = 0; i < BN / 32; i++) {
            int ci = i * 256 + tid;
            int r = ci >> 3, c = ci & 7;
            gload16(Wt + (size_t)(bn + r) * K + k0 + ((c ^ (r & 7)) * 8),
                    &Bsl[buf][ci * 8]);
        }
    };

    int nt = K / 64;
    stage(0, 0);
    __syncthreads();
    int cur = 0;
    for (int t = 0; t < nt; t++) {
        if (t + 1 < nt) stage(cur ^ 1, (t + 1) * 64);
#pragma unroll
        for (int ks = 0; ks < 2; ks++) {
            bf16x8 af[MR], bfr[NR];
#pragma unroll
            for (int mr = 0; mr < MR; mr++) {
                int ar = wm * SM + mr * 16 + l15;
                af[mr] = *(const bf16x8*)&Asl[cur][ar * 64 + ((((ks << 2) | l4) ^ (ar & 7)) * 8)];
            }
#pragma unroll
            for (int nr = 0; nr < NR; nr++) {
                int br = wn * SN + nr * 16 + l15;
                bfr[nr] = *(const bf16x8*)&Bsl[cur][br * 64 + ((((ks << 2) | l4) ^ (br & 7)) * 8)];
            }
#pragma unroll
            for (int mr = 0; mr < MR; mr++)
#pragma unroll
                for (int nr = 0; nr < NR; nr++)
                    acc[mr][nr] = __builtin_amdgcn_mfma_f32_16x16x32_bf16(af[mr], bfr[nr], acc[mr][nr], 0, 0, 0);
        }
        __syncthreads();
        cur ^= 1;
    }

#pragma unroll
    for (int mr = 0; mr < MR; mr++) {
#pragma unroll
        for (int nr = 0; nr < NR; nr++) {
            int col = bn + wn * SN + nr * 16 + l15;
            float bcol = bias[col];
#pragma unroll
            for (int r = 0; r < 4; r++) {
                int row = bm + wm * SM + mr * 16 + l4 * 4 + r;
                size_t off = (size_t)row * N + col;
                float v = acc[mr][nr][r] + bcol;
                if (MODE == 0) {
                    Cf[off] = v;
                } else if (MODE == 1) {
                    Cf[off] = resid[off] + fmaxf(v, 0.f);
                } else if (MODE == 2) {
                    float t3 = tanhf(0.7978845608028654f * (v + 0.044715f * v * v * v));
                    Cb[off] = f2b(0.5f * v * (1.f + t3));
                } else if (MODE == 3) {
                    Cf[off] = resid[off] + v;
                } else if (MODE == 4) {
                    Cf[off] = v;
                    Cb[off] = f2b(v);
                } else {
                    Cb[off] = f2b(v);
                }
            }
        }
    }

    // fused kn for the K region of qkv output (cols 512..1024)
    if (MODE == 5) {
        int cbase = bn + wn * SN;
        if (cbase >= 512 && cbase < 1024) {
            int hh = (cbase - 512) >> 6;
#pragma unroll
            for (int mr = 0; mr < MR; mr++) {
#pragma unroll
                for (int r = 0; r < 4; r++) {
                    float p = 0.f;
#pragma unroll
                    for (int nr = 0; nr < NR; nr++) {
                        float v = acc[mr][nr][r] + bias[cbase + nr * 16 + l15];
                        p += v * v;
                    }
                    p += __shfl_xor(p, 1, 64);
                    p += __shfl_xor(p, 2, 64);
                    p += __shfl_xor(p, 4, 64);
                    p += __shfl_xor(p, 8, 64);
                    if (l15 == 0) {
                        int row = bm + wm * SM + mr * 16 + l4 * 4 + r;
                        knout[row * NHEAD + hh] = p;
                    }
                }
            }
        }
    }
}

// ---------------- LayerNorm over D=512, one row per block ----------------
template <int OUTB>
__global__ __launch_bounds__(256) void ln_k(
    const float* __restrict__ X, const float* __restrict__ g,
    const float* __restrict__ bta, void* __restrict__ Yv, float eps)
{
    int row = blockIdx.x;
    int tid = threadIdx.x;
    const float* xr = X + (size_t)row * DMODEL;
    float v0 = xr[tid], v1 = xr[tid + 256];
    __shared__ float red[8];
    float s = wsum(v0 + v1);
    int wid = tid >> 6, lane = tid & 63;
    if (lane == 0) red[wid] = s;
    __syncthreads();
    float m = (red[0] + red[1] + red[2] + red[3]) * (1.f / DMODEL);
    float d0 = v0 - m, d1 = v1 - m;
    float sq = wsum(d0 * d0 + d1 * d1);
    if (lane == 0) red[4 + wid] = sq;
    __syncthreads();
    float var = (red[4] + red[5] + red[6] + red[7]) * (1.f / DMODEL);
    float rs = 1.0f / sqrtf(var + eps);
    float y0 = d0 * rs * g[tid] + bta[tid];
    float y1 = d1 * rs * g[tid + 256] + bta[tid + 256];
    if (OUTB) {
        unsigned short* Y = (unsigned short*)Yv;
        Y[(size_t)row * DMODEL + tid] = f2b(y0);
        Y[(size_t)row * DMODEL + tid + 256] = f2b(y1);
    } else {
        float* Y = (float*)Yv;
        Y[(size_t)row * DMODEL + tid] = y0;
        Y[(size_t)row * DMODEL + tid + 256] = y1;
    }
}

// ---------------- gathered attention, bf16 qkv, fixed-cost-balanced schedule --------
__global__ __launch_bounds__(256) void attn_k(
    const unsigned short* __restrict__ qkv,   // [n][1536] bf16
    const float* __restrict__ kn,             // [n][8]
    const int* __restrict__ indices, const float* __restrict__ dsel,
    const float* __restrict__ lam, unsigned short* __restrict__ xo, int layer)
{
    int xcd = blockIdx.x & 7;
    int t = blockIdx.x >> 3;
    int hh, blk;
    int c0 = g_s0cnt[xcd];
    if (t < c0) {
        hh = g_s0h[xcd]; blk = g_s0base[xcd] + t;
    } else {
        t -= c0;
        if (t < g_s1cnt[xcd]) {
            hh = g_s1h[xcd]; blk = t;
        } else {
            return;
        }
    }

    int wid = threadIdx.x >> 6, lane = threadIdx.x & 63;
    int n = blk * 4 + wid;
    int Kh = 32 + 16 * hh + (hh == 7 ? 16 : 0);   // 32..160, multiples of 16

    __shared__ __align__(16) unsigned qsp[4][32];   // q as packed bf16 pairs
    __shared__ float asc[4][KMAX];
    __shared__ int   sidx[4][KMAX];

    const unsigned short* qrow = qkv + (size_t)n * 1536 + hh * 64;
    float qd = b2f(qrow[lane]);
    if (lane < 32) qsp[wid][lane] = ((const unsigned*)qrow)[lane];
    float qn2 = wsum(qd * qd);
    float sp = log1pf(expf(lam[layer * NHEAD + hh]));

    const int* irow = indices + (size_t)n * KMAX;
    const float* drow = dsel + (size_t)n * KMAX;

    // ---- Phase A: 16 neighbors/iter, 4 lanes each; dot2; 2-deep pipeline ----
    int sub = lane & 3, grp = lane >> 2;
    const uint4* qp = (const uint4*)&qsp[wid][0];
    uint4 qa = qp[sub], qb = qp[4 + sub];

    int iters = Kh >> 4;
    int idxn = irow[grp];
    const uint4* krn = (const uint4*)(qkv + (size_t)idxn * 1536 + 512 + hh * 64);
    uint4 kan = krn[sub], kbn = krn[4 + sub];
    for (int it = 0; it < iters; it++) {
        int idxc = idxn;
        uint4 ka = kan, kb = kbn;
        if (it + 1 < iters) {
            idxn = irow[(it + 1) * 16 + grp];
            const uint4* kr = (const uint4*)(qkv + (size_t)idxn * 1536 + 512 + hh * 64);
            kan = kr[sub]; kbn = kr[4 + sub];
        }
        float d0 = 0.f, d1 = 0.f, d2 = 0.f, d3 = 0.f;
        d0 = dot2bf(ka.x, qa.x, d0); d1 = dot2bf(ka.y, qa.y, d1);
        d2 = dot2bf(ka.z, qa.z, d2); d3 = dot2bf(ka.w, qa.w, d3);
        d0 = dot2bf(kb.x, qb.x, d0); d1 = dot2bf(kb.y, qb.y, d1);
        d2 = dot2bf(kb.z, qb.z, d2); d3 = dot2bf(kb.w, qb.w, d3);
        float dp = (d0 + d1) + (d2 + d3);
        dp += __shfl_xor(dp, 1, 64);
        dp += __shfl_xor(dp, 2, 64);
        if (sub == 0) {
            int kk = it * 16 + grp;
            asc[wid][kk] = dp;
            sidx[wid][kk] = idxc;
        }
    }

    // ---- Phase B: finalize scores + softmax ----
    float s0 = -1e30f, s1 = -1e30f, s2 = -1e30f;
    {
        int kk = lane;
        if (kk < Kh) {
            float knv = kn[sidx[wid][kk] * NHEAD + hh];
            s0 = (asc[wid][kk] - 0.5f * (qn2 + knv)) * 0.125f - sp * drow[kk];
        }
        kk = lane + 64;
        if (kk < Kh) {
            float knv = kn[sidx[wid][kk] * NHEAD + hh];
            s1 = (asc[wid][kk] - 0.5f * (qn2 + knv)) * 0.125f - sp * drow[kk];
        }
        kk = lane + 128;
        if (kk < Kh) {
            float knv = kn[sidx[wid][kk] * NHEAD + hh];
            s2 = (asc[wid][kk] - 0.5f * (qn2 + knv)) * 0.125f - sp * drow[kk];
        }
    }
    float mx = wmax(fmaxf(fmaxf(s0, s1), s2));
    float e0 = (s0 > -1e29f) ? expf(s0 - mx) : 0.f;
    float e1 = (s1 > -1e29f) ? expf(s1 - mx) : 0.f;
    float e2 = (s2 > -1e29f) ? expf(s2 - mx) : 0.f;
    float se = wsum(e0 + e1 + e2);
    float inv = 1.f / se;
    if (lane < Kh)       asc[wid][lane]       = e0 * inv;
    if (lane + 64 < Kh)  asc[wid][lane + 64]  = e1 * inv;
    if (lane + 128 < Kh) asc[wid][lane + 128] = e2 * inv;

    // ---- Phase C: PV, 8 lanes per neighbor (lane = g*8+q), uint4 V loads ----
    int g = lane >> 3, q = lane & 7;
    const uint4* vb = (const uint4*)(qkv + 1024 + hh * 64 + q * 8);  // +idx*192 per row
    float a8[8] = {};
    int k0 = 0;
    int kmain = Kh & ~31;
    for (; k0 < kmain; k0 += 32) {
        int ii[4]; float aa[4]; uint4 vv[4];
#pragma unroll
        for (int u = 0; u < 4; u++) {
            int kk = k0 + u * 8 + g;
            ii[u] = sidx[wid][kk];
            aa[u] = asc[wid][kk];
        }
#pragma unroll
        for (int u = 0; u < 4; u++) vv[u] = vb[(size_t)ii[u] * 192];
#pragma unroll
        for (int u = 0; u < 4; u++) {
            const unsigned short* vp = (const unsigned short*)&vv[u];
#pragma unroll
            for (int d = 0; d < 8; d++) a8[d] += aa[u] * b2f(vp[d]);
        }
    }
    if (Kh & 16) {
        int ii[2]; float aa[2]; uint4 vv[2];
#pragma unroll
        for (int u = 0; u < 2; u++) {
            int kk = k0 + u * 8 + g;
            ii[u] = sidx[wid][kk];
            aa[u] = asc[wid][kk];
        }
#pragma unroll
        for (int u = 0; u < 2; u++) vv[u] = vb[(size_t)ii[u] * 192];
#pragma unroll
        for (int u = 0; u < 2; u++) {
            const unsigned short* vp = (const unsigned short*)&vv[u];
#pragma unroll
            for (int d = 0; d < 8; d++) a8[d] += aa[u] * b2f(vp[d]);
        }
    }
#pragma unroll
    for (int d = 0; d < 8; d++) {
        a8[d] += __shfl_xor(a8[d], 8, 64);
        a8[d] += __shfl_xor(a8[d], 16, 64);
        a8[d] += __shfl_xor(a8[d], 32, 64);
    }
    if (lane < 8) {
        unsigned o[4];
#pragma unroll
        for (int p = 0; p < 4; p++)
            o[p] = ((unsigned)f2b(a8[2 * p + 1]) << 16) | (unsigned)f2b(a8[2 * p]);
        *(uint4*)(xo + (size_t)n * DMODEL + hh * 64 + lane * 8) = *(uint4*)o;
    }
}

// ---------------- column partial sums ----------------
__global__ __launch_bounds__(512) void colpart_k(const float* __restrict__ Y, float* __restrict__ part)
{
    int c = threadIdx.x;
    int blk = blockIdx.x;
    const float* p = Y + (size_t)blk * 16 * DMODEL + c;
    float s = 0.f;
#pragma unroll
    for (int r = 0; r < 16; r++) s += p[r * DMODEL];
    part[blk * DMODEL + c] = s;
}

// ---------------- finish mean + head GEMV ----------------
__global__ __launch_bounds__(512) void finhead_k(
    const float* __restrict__ part, const float* __restrict__ head_w,
    const float* __restrict__ head_b, float* __restrict__ out)
{
    __shared__ float mv[DMODEL];
    int c = threadIdx.x;
    float s = 0.f;
    for (int i = 0; i < 256; i++) s += part[i * DMODEL + c];
    mv[c] = s * (1.f / NTOK);
    __syncthreads();
    if (c < 64) {
        float a0 = 0.f, a1 = 0.f;
        for (int d = c; d < DMODEL; d += 64) {
            float m = mv[d];
            a0 += m * head_w[d * NCLS + 0];
            a1 += m * head_w[d * NCLS + 1];
        }
        a0 = wsum(a0);
        a1 = wsum(a1);
        if (c == 0) { out[0] = a0 + head_b[0]; out[1] = a1 + head_b[1]; }
    }
}

extern "C" void kernel_launch(void* const* d_in, const int* in_sizes, int n_in,
                              void* d_out, int out_size, void* d_ws, size_t ws_size,
                              hipStream_t stream)
{
    const float* x        = (const float*)d_in[0];
    const float* distance = (const float*)d_in[1];
    const int*   indices  = (const int*)d_in[2];
    const float* adapter_w = (const float*)d_in[5];
    const float* adapter_b = (const float*)d_in[6];
    const float* res_w     = (const float*)d_in[7];
    const float* res_b     = (const float*)d_in[8];
    const float* ln1_g     = (const float*)d_in[9];
    const float* ln1_b     = (const float*)d_in[10];
    const float* qkv_w     = (const float*)d_in[11];
    const float* qkv_b     = (const float*)d_in[12];
    const float* proj_w    = (const float*)d_in[13];
    const float* proj_b    = (const float*)d_in[14];
    const float* ln2_g     = (const float*)d_in[15];
    const float* ln2_b     = (const float*)d_in[16];
    const float* fc1_w     = (const float*)d_in[17];
    const float* fc1_b     = (const float*)d_in[18];
    const float* fc2_w     = (const float*)d_in[19];
    const float* fc2_b     = (const float*)d_in[20];
    const float* lam       = (const float*)d_in[21];
    const float* lnf_g     = (const float*)d_in[22];
    const float* lnf_b     = (const float*)d_in[23];
    const float* head_w    = (const float*)d_in[24];
    const float* head_b    = (const float*)d_in[25];
    float* out = (float*)d_out;

    char* wsb = (char*)d_ws;
    float* h   = (float*)(wsb);                         // 8 MB
    float* h0  = (float*)(wsb + (8u << 20));            // 8 MB; dead during layers -> dsel
    float* dsel = (float*)(wsb + (8u << 20));           // 2.6 MB
    char* shared = wsb + (16u << 20);                   // 24 MB shared region
    unsigned short* xb    = (unsigned short*)shared;                // 8 MB (dead after adapter)
    unsigned short* qkvbb = (unsigned short*)shared;                // 12 MB bf16
    unsigned short* fc1b  = (unsigned short*)shared;                // 16 MB (after attn)
    unsigned short* adapter_wt = (unsigned short*)(shared + (8u << 20));  // 1 MB
    unsigned short* res_wt     = (unsigned short*)(shared + (9u << 20));  // 0.5 MB
    unsigned short* lnb  = (unsigned short*)(wsb + (40u << 20));    // 4 MB (also h0b)
    unsigned short* h0b  = lnb;
    unsigned short* xob  = (unsigned short*)(wsb + (44u << 20));    // 4 MB
    unsigned short* qkv_wt = (unsigned short*)(wsb + (48u << 20));  // 3 MB
    unsigned short* proj_wt = (unsigned short*)(wsb + (51u << 20)); // 1 MB
    unsigned short* fc1_wt  = (unsigned short*)(wsb + (52u << 20)); // 4 MB
    unsigned short* fc2_wt  = (unsigned short*)(wsb + (56u << 20)); // 4 MB
    float* kn   = (float*)(wsb + (60u << 20));                      // 128 KB
    float* part = (float*)(wsb + (60u << 20) + (1u << 18));         // 512 KB

    dim3 blk(256);

    // --- prep: all weight conversions + x->bf16 in ONE dispatch ---
    {
        Prep p;
        p.s[0] = { adapter_w, adapter_wt, EMB,    DMODEL, 0 };
        p.s[1] = { res_w,     res_wt,     DMODEL, DMODEL, 128 };
        p.s[2] = { qkv_w,     qkv_wt,     DMODEL, 1536,   192 };
        p.s[3] = { proj_w,    proj_wt,    DMODEL, DMODEL, 576 };
        p.s[4] = { fc1_w,     fc1_wt,     DMODEL, 2048,   704 };
        p.s[5] = { fc2_w,     fc2_wt,     2048,   DMODEL, 1216 };
        p.x = x; p.xb = xb; p.xtile0 = 1728;
        prep_k<<<1728 + (NTOK * EMB) / 2048, blk, 0, stream>>>(p);
    }

    // --- adapter: h0 = x @ adapter_w + b ---
    mgemm_k<64, 64, 2, 2, 4><<<dim3(NTOK / 64, DMODEL / 64), blk, 0, stream>>>(
        xb, adapter_wt, adapter_b, nullptr, h0, h0b, nullptr, NTOK, DMODEL, EMB);
    // --- h = h0 + relu(h0 @ res_w + b) ---
    mgemm_k<64, 64, 2, 2, 1><<<dim3(NTOK / 64, DMODEL / 64), blk, 0, stream>>>(
        h0b, res_wt, res_b, h0, h, nullptr, nullptr, NTOK, DMODEL, DMODEL);

    // dsel: h0 now dead until lnf
    dsel_k<<<NTOK, blk, 0, stream>>>(distance, indices, dsel);

    for (int l = 0; l < NLAYER; l++) {
        ln_k<1><<<NTOK, blk, 0, stream>>>(h, ln1_g + l * DMODEL, ln1_b + l * DMODEL, lnb, 1e-5f);
        mgemm_k<64, 128, 2, 2, 5><<<dim3(NTOK / 64, 1536 / 128), blk, 0, stream>>>(
            lnb, qkv_wt + (size_t)l * 1536 * DMODEL, qkv_b + l * 1536, nullptr,
            nullptr, qkvbb, kn, NTOK, 1536, DMODEL);
        attn_k<<<ATTN_BLOCKS, blk, 0, stream>>>(qkvbb, kn, indices, dsel, lam, xob, l);
        mgemm_k<64, 64, 2, 2, 3><<<dim3(NTOK / 64, DMODEL / 64), blk, 0, stream>>>(
            xob, proj_wt + (size_t)l * DMODEL * DMODEL, proj_b + l * DMODEL, h,
            h, nullptr, nullptr, NTOK, DMODEL, DMODEL);
        ln_k<1><<<NTOK, blk, 0, stream>>>(h, ln2_g + l * DMODEL, ln2_b + l * DMODEL, lnb, 1e-5f);
        mgemm_k<64, 128, 2, 2, 2><<<dim3(NTOK / 64, 2048 / 128), blk, 0, stream>>>(
            lnb, fc1_wt + (size_t)l * 2048 * DMODEL, fc1_b + l * 2048, nullptr,
            nullptr, fc1b, nullptr, NTOK, 2048, DMODEL);
        mgemm_k<64, 64, 2, 2, 3><<<dim3(NTOK / 64, DMODEL / 64), blk, 0, stream>>>(
            fc1b, fc2_wt + (size_t)l * DMODEL * 2048, fc2_b + l * DMODEL, h,
            h, nullptr, nullptr, NTOK, DMODEL, 2048);
    }

    ln_k<0><<<NTOK, blk, 0, stream>>>(h, lnf_g, lnf_b, h0, 1e-6f);
    colpart_k<<<256, 512, 0, stream>>>(h0, part);
    finhead_k<<<1, 512, 0, stream>>>(part, head_w, head_b, out);
}